// Round 1
// baseline (670.618 us; speedup 1.0000x reference)
//
#include <hip/hip_runtime.h>
#include <hip/hip_bf16.h>

#define Tt 2048
#define Dd 2048
#define Ff 512
#define Ee 16
#define NE 17            // 16 routed experts + 1 shared
#define KC (NE * Ff)     // 8704 concatenated K for the down GEMM

typedef __attribute__((ext_vector_type(8))) short short8;
typedef __attribute__((ext_vector_type(4))) float floatx4;

#define AS1 __attribute__((address_space(1)))
#define AS3 __attribute__((address_space(3)))

__device__ __forceinline__ unsigned short f2bf(float f) {
    union { float f; unsigned u; } v; v.f = f;
    unsigned r = v.u + 0x7FFFu + ((v.u >> 16) & 1u);   // RNE
    return (unsigned short)(r >> 16);
}

__device__ __forceinline__ void gld16(const unsigned short* g, unsigned short* l) {
    __builtin_amdgcn_global_load_lds((const AS1 void*)g, (AS3 void*)l, 16, 0, 0);
}

// ---------------- cast x -> bf16 ----------------
__global__ void cast_x_kernel(const float* __restrict__ x, unsigned short* __restrict__ xb) {
    int i = (blockIdx.x * 256 + threadIdx.x) * 4;
    floatx4 v = *(const floatx4*)(x + i);
    ushort4 o;
    o.x = f2bf(v.x); o.y = f2bf(v.y); o.z = f2bf(v.z); o.w = f2bf(v.w);
    *(ushort4*)(xb + i) = o;
}

// ---------------- transpose+cast weights ----------------
// dst[c * dstStride + r] = bf16(src[r * C + c]), src per expert z (z==16 -> shared)
__global__ void transpose_cast(const float* __restrict__ Wsrc, const float* __restrict__ Ssrc,
                               unsigned short* __restrict__ dst, int R, int C,
                               size_t dstEOff, int dstStride) {
    __shared__ float tile[32][33];
    int z = blockIdx.z;
    const float* src = (z < Ee) ? (Wsrc + (size_t)z * R * C) : Ssrc;
    unsigned short* d = dst + (size_t)z * dstEOff;
    int c0 = blockIdx.x * 32;
    int r0 = blockIdx.y * 32;
    int tx = threadIdx.x & 31, ty = threadIdx.x >> 5;   // 32 x 8
#pragma unroll
    for (int i = 0; i < 4; i++) {
        int r = r0 + ty + i * 8;
        tile[ty + i * 8][tx] = src[(size_t)r * C + c0 + tx];
    }
    __syncthreads();
#pragma unroll
    for (int i = 0; i < 4; i++) {
        int c = c0 + ty + i * 8;
        d[(size_t)c * dstStride + r0 + tx] = f2bf(tile[tx][ty + i * 8]);
    }
}

// ---------------- router: softmax + top4 + renorm + shared sigmoid gate ----------------
__global__ void router_kernel(const float* __restrict__ x, const float* __restrict__ gw,
                              const float* __restrict__ sgw, float* __restrict__ comb) {
    const int t = blockIdx.x;
    const int lane = threadIdx.x;                      // 64 threads
    const float* xp = x + (size_t)t * Dd;
    float xr[32];
#pragma unroll
    for (int j = 0; j < 32; j++) xr[j] = xp[lane + j * 64];
    float lg[NE];
    for (int e = 0; e < Ee; e++) {
        const float* g = gw + (size_t)e * Dd;
        float s = 0.f;
#pragma unroll
        for (int j = 0; j < 32; j++) s += xr[j] * g[lane + j * 64];
        lg[e] = s;
    }
    {
        float s = 0.f;
#pragma unroll
        for (int j = 0; j < 32; j++) s += xr[j] * sgw[lane + j * 64];
        lg[Ee] = s;
    }
#pragma unroll
    for (int e = 0; e < NE; e++) {
        float s = lg[e];
        s += __shfl_xor(s, 32); s += __shfl_xor(s, 16); s += __shfl_xor(s, 8);
        s += __shfl_xor(s, 4);  s += __shfl_xor(s, 2);  s += __shfl_xor(s, 1);
        lg[e] = s;
    }
    if (lane == 0) {
        float mx = lg[0];
        for (int e = 1; e < Ee; e++) mx = fmaxf(mx, lg[e]);
        float p[Ee]; float sum = 0.f;
        for (int e = 0; e < Ee; e++) { p[e] = __expf(lg[e] - mx); sum += p[e]; }
        float inv = 1.f / sum;
        for (int e = 0; e < Ee; e++) p[e] *= inv;
        bool sel[Ee];
        for (int e = 0; e < Ee; e++) sel[e] = false;
        float ssum = 0.f;
        for (int k = 0; k < 4; k++) {
            int bi = 0; float bv = -1.f;
            for (int e = 0; e < Ee; e++)
                if (!sel[e] && p[e] > bv) { bv = p[e]; bi = e; }
            sel[bi] = true; ssum += bv;
        }
        float rinv = 1.f / ssum;
        for (int e = 0; e < Ee; e++) comb[t * NE + e] = sel[e] ? p[e] * rinv : 0.f;
        comb[t * NE + Ee] = 1.f / (1.f + __expf(-lg[Ee]));
    }
}

// ---------------- GEMM1: H[t][e*F+f] = comb[t][e] * silu(x@Wg_e) * (x@Wu_e) ----------------
// A = xb [T][D] bf16, B^T = WgT/WuT [NE][F][D] bf16. 128x128 tile, BK=32, 4 waves 2x2.
__global__ __launch_bounds__(256, 2) void gemm1_kernel(
    const unsigned short* __restrict__ xb,
    const unsigned short* __restrict__ WgT,
    const unsigned short* __restrict__ WuT,
    const float* __restrict__ comb,
    unsigned short* __restrict__ H)
{
    __shared__ unsigned short sA[128 * 32];
    __shared__ unsigned short sG[128 * 32];
    __shared__ unsigned short sU[128 * 32];
    const int e  = blockIdx.z;
    const int m0 = blockIdx.y * 128;
    const int n0 = blockIdx.x * 128;
    const int tid = threadIdx.x;
    const int lane = tid & 63, wv = tid >> 6;
    const int wm = (wv >> 1) * 64, wn = (wv & 1) * 64;
    const int lr = lane & 15, quad = lane >> 4;

    const unsigned short* Ab = xb + (size_t)m0 * Dd;
    const unsigned short* Gb = WgT + (size_t)e * Ff * Dd + (size_t)n0 * Dd;
    const unsigned short* Ub = WuT + (size_t)e * Ff * Dd + (size_t)n0 * Dd;

    const int l0 = tid * 8;                 // element offset in [128][32] tile
    const int r0 = l0 >> 5, c0 = l0 & 31;
    const int l1 = l0 + 2048;
    const int r1 = r0 + 64;

    floatx4 accg[4][4], accu[4][4];
#pragma unroll
    for (int i = 0; i < 4; i++)
#pragma unroll
        for (int j = 0; j < 4; j++) {
            accg[i][j] = (floatx4){0.f, 0.f, 0.f, 0.f};
            accu[i][j] = (floatx4){0.f, 0.f, 0.f, 0.f};
        }

    for (int k0 = 0; k0 < Dd; k0 += 32) {
        __syncthreads();
        gld16(Ab + (size_t)r0 * Dd + k0 + c0, &sA[l0]);
        gld16(Ab + (size_t)r1 * Dd + k0 + c0, &sA[l1]);
        gld16(Gb + (size_t)r0 * Dd + k0 + c0, &sG[l0]);
        gld16(Gb + (size_t)r1 * Dd + k0 + c0, &sG[l1]);
        gld16(Ub + (size_t)r0 * Dd + k0 + c0, &sU[l0]);
        gld16(Ub + (size_t)r1 * Dd + k0 + c0, &sU[l1]);
        __syncthreads();
        short8 af[4];
#pragma unroll
        for (int i = 0; i < 4; i++)
            af[i] = *(const short8*)&sA[(wm + i * 16 + lr) * 32 + quad * 8];
#pragma unroll
        for (int j = 0; j < 4; j++) {
            short8 bg = *(const short8*)&sG[(wn + j * 16 + lr) * 32 + quad * 8];
            short8 bu = *(const short8*)&sU[(wn + j * 16 + lr) * 32 + quad * 8];
#pragma unroll
            for (int i = 0; i < 4; i++) {
                accg[i][j] = __builtin_amdgcn_mfma_f32_16x16x32_bf16(af[i], bg, accg[i][j], 0, 0, 0);
                accu[i][j] = __builtin_amdgcn_mfma_f32_16x16x32_bf16(af[i], bu, accu[i][j], 0, 0, 0);
            }
        }
    }
    // epilogue: C/D layout col=lane&15, row=quad*4+reg
#pragma unroll
    for (int i = 0; i < 4; i++) {
#pragma unroll
        for (int r = 0; r < 4; r++) {
            const int t = m0 + wm + i * 16 + quad * 4 + r;
            const float wc = comb[t * NE + e];
#pragma unroll
            for (int j = 0; j < 4; j++) {
                const float g = accg[i][j][r];
                const float u = accu[i][j][r];
                const float h = (g / (1.f + __expf(-g))) * u * wc;
                H[(size_t)t * KC + e * Ff + (n0 + wn + j * 16 + lr)] = f2bf(h);
            }
        }
    }
}

// ---------------- GEMM2: out = H[T][KC] @ WdCat[KC][D], split-K=2, atomic fp32 ----------------
__global__ __launch_bounds__(256, 2) void gemm2_kernel(
    const unsigned short* __restrict__ H,
    const unsigned short* __restrict__ WdT,   // [D][KC] = B^T
    float* __restrict__ out)
{
    __shared__ unsigned short sA[128 * 32];
    __shared__ unsigned short sB[128 * 32];
    const int m0 = blockIdx.y * 128;
    const int n0 = blockIdx.x * 128;
    const int kb = blockIdx.z * (KC / 2);
    const int ke = kb + KC / 2;
    const int tid = threadIdx.x;
    const int lane = tid & 63, wv = tid >> 6;
    const int wm = (wv >> 1) * 64, wn = (wv & 1) * 64;
    const int lr = lane & 15, quad = lane >> 4;

    const unsigned short* Ab = H + (size_t)m0 * KC;
    const unsigned short* Bb = WdT + (size_t)n0 * KC;

    const int l0 = tid * 8;
    const int r0 = l0 >> 5, c0 = l0 & 31;
    const int l1 = l0 + 2048;
    const int r1 = r0 + 64;

    floatx4 acc[4][4];
#pragma unroll
    for (int i = 0; i < 4; i++)
#pragma unroll
        for (int j = 0; j < 4; j++) acc[i][j] = (floatx4){0.f, 0.f, 0.f, 0.f};

    for (int k0 = kb; k0 < ke; k0 += 32) {
        __syncthreads();
        gld16(Ab + (size_t)r0 * KC + k0 + c0, &sA[l0]);
        gld16(Ab + (size_t)r1 * KC + k0 + c0, &sA[l1]);
        gld16(Bb + (size_t)r0 * KC + k0 + c0, &sB[l0]);
        gld16(Bb + (size_t)r1 * KC + k0 + c0, &sB[l1]);
        __syncthreads();
        short8 af[4];
#pragma unroll
        for (int i = 0; i < 4; i++)
            af[i] = *(const short8*)&sA[(wm + i * 16 + lr) * 32 + quad * 8];
#pragma unroll
        for (int j = 0; j < 4; j++) {
            short8 bf = *(const short8*)&sB[(wn + j * 16 + lr) * 32 + quad * 8];
#pragma unroll
            for (int i = 0; i < 4; i++)
                acc[i][j] = __builtin_amdgcn_mfma_f32_16x16x32_bf16(af[i], bf, acc[i][j], 0, 0, 0);
        }
    }
#pragma unroll
    for (int i = 0; i < 4; i++) {
#pragma unroll
        for (int r = 0; r < 4; r++) {
            const int t = m0 + wm + i * 16 + quad * 4 + r;
#pragma unroll
            for (int j = 0; j < 4; j++) {
                atomicAdd(&out[(size_t)t * Dd + (n0 + wn + j * 16 + lr)], acc[i][j][r]);
            }
        }
    }
}

extern "C" void kernel_launch(void* const* d_in, const int* in_sizes, int n_in,
                              void* d_out, int out_size, void* d_ws, size_t ws_size,
                              hipStream_t stream) {
    const float* x   = (const float*)d_in[0];
    const float* gw  = (const float*)d_in[1];
    const float* Wg  = (const float*)d_in[2];
    const float* Wu  = (const float*)d_in[3];
    const float* Wd  = (const float*)d_in[4];
    const float* sWg = (const float*)d_in[5];
    const float* sWu = (const float*)d_in[6];
    const float* sWd = (const float*)d_in[7];
    const float* sgw = (const float*)d_in[8];
    float* out = (float*)d_out;

    // workspace layout (bytes)
    char* ws = (char*)d_ws;
    unsigned short* xb  = (unsigned short*)(ws);                 //  8,388,608  x bf16 [T][D]
    unsigned short* WgT = (unsigned short*)(ws + 8388608);       // 35,651,584  [NE][F][D]
    unsigned short* WuT = (unsigned short*)(ws + 44040192);      // 35,651,584  [NE][F][D]
    unsigned short* WdT = (unsigned short*)(ws + 79691776);      // 35,651,584  [D][KC]
    unsigned short* Hb  = (unsigned short*)(ws + 115343360);     // 35,651,584  [T][KC]
    float*          comb = (float*)(ws + 150994944);             //    139,264  [T][NE]

    cast_x_kernel<<<4096, 256, 0, stream>>>(x, xb);
    // Wg/Wu: src [D][F] -> dst [F][D] per expert (stride D, expert off F*D)
    transpose_cast<<<dim3(16, 64, 17), 256, 0, stream>>>(Wg, sWg, WgT, Dd, Ff, (size_t)Ff * Dd, Dd);
    transpose_cast<<<dim3(16, 64, 17), 256, 0, stream>>>(Wu, sWu, WuT, Dd, Ff, (size_t)Ff * Dd, Dd);
    // Wd: src [F][D] -> dst [D][KC] slice at col z*F (stride KC, expert off F)
    transpose_cast<<<dim3(64, 16, 17), 256, 0, stream>>>(Wd, sWd, WdT, Ff, Dd, (size_t)Ff, KC);
    router_kernel<<<Tt, 64, 0, stream>>>(x, gw, sgw, comb);
    gemm1_kernel<<<dim3(4, 16, 17), 256, 0, stream>>>(xb, WgT, WuT, comb, Hb);
    hipMemsetAsync(out, 0, (size_t)Tt * Dd * sizeof(float), stream);
    gemm2_kernel<<<dim3(16, 16, 2), 256, 0, stream>>>(Hb, WdT, out);
}

// Round 2
// 639.331 us; speedup vs baseline: 1.0489x; 1.0489x over previous
//
#include <hip/hip_runtime.h>
#include <hip/hip_bf16.h>

#define Tt 2048
#define Dd 2048
#define Ff 512
#define Ee 16
#define NE 17                    // 16 routed experts + 1 shared
#define MAXROWS (NE * Tt)        // 34816 worst-case padded packed rows
#define MAXTILES (MAXROWS / 128) // 272

typedef __attribute__((ext_vector_type(8))) short short8;
typedef __attribute__((ext_vector_type(4))) float floatx4;

#define AS1 __attribute__((address_space(1)))
#define AS3 __attribute__((address_space(3)))

__device__ __forceinline__ unsigned short f2bf(float f) {
    union { float f; unsigned u; } v; v.f = f;
    unsigned r = v.u + 0x7FFFu + ((v.u >> 16) & 1u);   // RNE
    return (unsigned short)(r >> 16);
}

__device__ __forceinline__ void gld16(const unsigned short* g, unsigned short* l) {
    __builtin_amdgcn_global_load_lds((const AS1 void*)g, (AS3 void*)l, 16, 0, 0);
}

// ---------------- cast x -> bf16 ----------------
__global__ void cast_x_kernel(const float* __restrict__ x, unsigned short* __restrict__ xb) {
    int i = (blockIdx.x * 256 + threadIdx.x) * 4;
    floatx4 v = *(const floatx4*)(x + i);
    ushort4 o;
    o.x = f2bf(v.x); o.y = f2bf(v.y); o.z = f2bf(v.z); o.w = f2bf(v.w);
    *(ushort4*)(xb + i) = o;
}

// ---------------- transpose+cast weights ----------------
// dst[c * dstStride + r] = bf16(src[r * C + c]), src per expert z (z==16 -> shared)
__global__ void transpose_cast(const float* __restrict__ Wsrc, const float* __restrict__ Ssrc,
                               unsigned short* __restrict__ dst, int R, int C,
                               size_t dstEOff, int dstStride) {
    __shared__ float tile[32][33];
    int z = blockIdx.z;
    const float* src = (z < Ee) ? (Wsrc + (size_t)z * R * C) : Ssrc;
    unsigned short* d = dst + (size_t)z * dstEOff;
    int c0 = blockIdx.x * 32;
    int r0 = blockIdx.y * 32;
    int tx = threadIdx.x & 31, ty = threadIdx.x >> 5;   // 32 x 8
#pragma unroll
    for (int i = 0; i < 4; i++) {
        int r = r0 + ty + i * 8;
        tile[ty + i * 8][tx] = src[(size_t)r * C + c0 + tx];
    }
    __syncthreads();
#pragma unroll
    for (int i = 0; i < 4; i++) {
        int c = c0 + ty + i * 8;
        d[(size_t)c * dstStride + r0 + tx] = f2bf(tile[tx][ty + i * 8]);
    }
}

// ---------------- router: softmax + top4 + renorm + shared sigmoid gate ----------------
__global__ void router_kernel(const float* __restrict__ x, const float* __restrict__ gw,
                              const float* __restrict__ sgw, float* __restrict__ comb,
                              int* __restrict__ selids, int* __restrict__ counts) {
    const int t = blockIdx.x;
    const int lane = threadIdx.x;                      // 64 threads
    const float* xp = x + (size_t)t * Dd;
    float xr[32];
#pragma unroll
    for (int j = 0; j < 32; j++) xr[j] = xp[lane + j * 64];
    float lg[NE];
    for (int e = 0; e < Ee; e++) {
        const float* g = gw + (size_t)e * Dd;
        float s = 0.f;
#pragma unroll
        for (int j = 0; j < 32; j++) s += xr[j] * g[lane + j * 64];
        lg[e] = s;
    }
    {
        float s = 0.f;
#pragma unroll
        for (int j = 0; j < 32; j++) s += xr[j] * sgw[lane + j * 64];
        lg[Ee] = s;
    }
#pragma unroll
    for (int e = 0; e < NE; e++) {
        float s = lg[e];
        s += __shfl_xor(s, 32); s += __shfl_xor(s, 16); s += __shfl_xor(s, 8);
        s += __shfl_xor(s, 4);  s += __shfl_xor(s, 2);  s += __shfl_xor(s, 1);
        lg[e] = s;
    }
    if (lane == 0) {
        float mx = lg[0];
        for (int e = 1; e < Ee; e++) mx = fmaxf(mx, lg[e]);
        float p[Ee]; float sum = 0.f;
        for (int e = 0; e < Ee; e++) { p[e] = __expf(lg[e] - mx); sum += p[e]; }
        float inv = 1.f / sum;
        for (int e = 0; e < Ee; e++) p[e] *= inv;
        bool sel[Ee];
        for (int e = 0; e < Ee; e++) sel[e] = false;
        int ids[4];
        float ssum = 0.f;
        for (int k = 0; k < 4; k++) {
            int bi = 0; float bv = -1.f;
            for (int e = 0; e < Ee; e++)
                if (!sel[e] && p[e] > bv) { bv = p[e]; bi = e; }
            sel[bi] = true; ids[k] = bi; ssum += bv;
        }
        float rinv = 1.f / ssum;
        for (int e = 0; e < Ee; e++) comb[t * NE + e] = sel[e] ? p[e] * rinv : 0.f;
        comb[t * NE + Ee] = 1.f / (1.f + __expf(-lg[Ee]));
        for (int k = 0; k < 4; k++) {
            selids[t * 4 + k] = ids[k];
            atomicAdd(&counts[ids[k]], 1);
        }
    }
}

// ---------------- offsets: tile-padded exclusive scan + block table ----------------
__global__ void offsets_kernel(const int* __restrict__ counts, int* __restrict__ off,
                               int* __restrict__ cursor, int* __restrict__ blocktab,
                               int* __restrict__ meta) {
    int acc = 0, nt = 0;
    for (int e = 0; e < NE; e++) {
        int c = (e < Ee) ? counts[e] : Tt;
        off[e] = acc;
        if (e < Ee) cursor[e] = 0;
        int tiles = (c + 127) >> 7;
        for (int tl = 0; tl < tiles; tl++) blocktab[nt++] = (e << 20) | (acc + tl * 128);
        acc += tiles << 7;
    }
    meta[0] = nt;
}

// ---------------- scatter: build rowmap (packed position -> token) ----------------
__global__ void scatter_kernel(const int* __restrict__ selids, const int* __restrict__ off,
                               int* __restrict__ cursor, int* __restrict__ rowmap) {
    int t = blockIdx.x * 256 + threadIdx.x;
    if (t >= Tt) return;
#pragma unroll
    for (int k = 0; k < 4; k++) {
        int e = selids[t * 4 + k];
        int r = atomicAdd(&cursor[e], 1);
        rowmap[off[e] + r] = t;
    }
    rowmap[off[Ee] + t] = t;    // shared expert: identity
}

// ---------------- GEMM1: Hp[pos][f] = comb * silu(x@Wg_e) * (x@Wu_e), grouped ----------------
__global__ __launch_bounds__(256, 2) void gemm1_kernel(
    const unsigned short* __restrict__ xb,
    const unsigned short* __restrict__ WgT,
    const unsigned short* __restrict__ WuT,
    const float* __restrict__ comb,
    const int* __restrict__ rowmap,
    const int* __restrict__ blocktab,
    const int* __restrict__ meta,
    unsigned short* __restrict__ Hp)
{
    if ((int)blockIdx.y >= meta[0]) return;
    __shared__ unsigned short sA[128 * 32];
    __shared__ unsigned short sG[128 * 32];
    __shared__ unsigned short sU[128 * 32];
    const int info = blocktab[blockIdx.y];
    const int e  = info >> 20;
    const int m0 = info & 0xFFFFF;
    const int n0 = blockIdx.x * 128;
    const int tid = threadIdx.x;
    const int lane = tid & 63, wv = tid >> 6;
    const int wm = (wv >> 1) * 64, wn = (wv & 1) * 64;
    const int lr = lane & 15, quad = lane >> 4;

    const unsigned short* Gb = WgT + (size_t)e * Ff * Dd + (size_t)n0 * Dd;
    const unsigned short* Ub = WuT + (size_t)e * Ff * Dd + (size_t)n0 * Dd;

    const int l0 = tid * 8;                 // element offset in [128][32] tile
    const int r0 = l0 >> 5, c0 = l0 & 31;
    const int l1 = l0 + 2048;
    const int r1 = r0 + 64;

    // indirect A rows (padded slots -> token 0, weight forced to 0 in epilogue)
    const int tk0 = rowmap[m0 + r0];
    const int tk1 = rowmap[m0 + r1];
    const unsigned short* a0 = xb + (size_t)(tk0 < 0 ? 0 : tk0) * Dd + c0;
    const unsigned short* a1 = xb + (size_t)(tk1 < 0 ? 0 : tk1) * Dd + c0;

    floatx4 accg[4][4], accu[4][4];
#pragma unroll
    for (int i = 0; i < 4; i++)
#pragma unroll
        for (int j = 0; j < 4; j++) {
            accg[i][j] = (floatx4){0.f, 0.f, 0.f, 0.f};
            accu[i][j] = (floatx4){0.f, 0.f, 0.f, 0.f};
        }

    for (int k0 = 0; k0 < Dd; k0 += 32) {
        __syncthreads();
        gld16(a0 + k0, &sA[l0]);
        gld16(a1 + k0, &sA[l1]);
        gld16(Gb + (size_t)r0 * Dd + k0 + c0, &sG[l0]);
        gld16(Gb + (size_t)r1 * Dd + k0 + c0, &sG[l1]);
        gld16(Ub + (size_t)r0 * Dd + k0 + c0, &sU[l0]);
        gld16(Ub + (size_t)r1 * Dd + k0 + c0, &sU[l1]);
        __syncthreads();
        short8 af[4];
#pragma unroll
        for (int i = 0; i < 4; i++)
            af[i] = *(const short8*)&sA[(wm + i * 16 + lr) * 32 + quad * 8];
#pragma unroll
        for (int j = 0; j < 4; j++) {
            short8 bg = *(const short8*)&sG[(wn + j * 16 + lr) * 32 + quad * 8];
            short8 bu = *(const short8*)&sU[(wn + j * 16 + lr) * 32 + quad * 8];
#pragma unroll
            for (int i = 0; i < 4; i++) {
                accg[i][j] = __builtin_amdgcn_mfma_f32_16x16x32_bf16(af[i], bg, accg[i][j], 0, 0, 0);
                accu[i][j] = __builtin_amdgcn_mfma_f32_16x16x32_bf16(af[i], bu, accu[i][j], 0, 0, 0);
            }
        }
    }
    // epilogue: C/D layout col=lane&15, row=quad*4+reg
#pragma unroll
    for (int i = 0; i < 4; i++) {
#pragma unroll
        for (int r = 0; r < 4; r++) {
            const int pos = m0 + wm + i * 16 + quad * 4 + r;
            const int tok = rowmap[pos];
            const float wc = (tok >= 0) ? comb[tok * NE + e] : 0.f;
#pragma unroll
            for (int j = 0; j < 4; j++) {
                const float g = accg[i][j][r];
                const float u = accu[i][j][r];
                const float h = (g / (1.f + __expf(-g))) * u * wc;
                Hp[(size_t)pos * Ff + (n0 + wn + j * 16 + lr)] = f2bf(h);
            }
        }
    }
}

// ---------------- GEMM2: out[tok] += Hp[pos] @ Wd_e, grouped, scatter-atomic ----------------
__global__ __launch_bounds__(256, 2) void gemm2_kernel(
    const unsigned short* __restrict__ Hp,
    const unsigned short* __restrict__ WdT,   // [NE][D][F]  (B^T per expert)
    const int* __restrict__ rowmap,
    const int* __restrict__ blocktab,
    const int* __restrict__ meta,
    float* __restrict__ out)
{
    if ((int)blockIdx.y >= meta[0]) return;
    __shared__ unsigned short sA[128 * 32];
    __shared__ unsigned short sB[128 * 32];
    const int info = blocktab[blockIdx.y];
    const int e  = info >> 20;
    const int m0 = info & 0xFFFFF;
    const int n0 = blockIdx.x * 128;
    const int tid = threadIdx.x;
    const int lane = tid & 63, wv = tid >> 6;
    const int wm = (wv >> 1) * 64, wn = (wv & 1) * 64;
    const int lr = lane & 15, quad = lane >> 4;

    const unsigned short* Ab = Hp + (size_t)m0 * Ff;
    const unsigned short* Bb = WdT + (size_t)e * Dd * Ff + (size_t)n0 * Ff;

    const int l0 = tid * 8;
    const int r0 = l0 >> 5, c0 = l0 & 31;
    const int l1 = l0 + 2048;
    const int r1 = r0 + 64;

    floatx4 acc[4][4];
#pragma unroll
    for (int i = 0; i < 4; i++)
#pragma unroll
        for (int j = 0; j < 4; j++) acc[i][j] = (floatx4){0.f, 0.f, 0.f, 0.f};

    for (int k0 = 0; k0 < Ff; k0 += 32) {
        __syncthreads();
        gld16(Ab + (size_t)r0 * Ff + k0 + c0, &sA[l0]);
        gld16(Ab + (size_t)r1 * Ff + k0 + c0, &sA[l1]);
        gld16(Bb + (size_t)r0 * Ff + k0 + c0, &sB[l0]);
        gld16(Bb + (size_t)r1 * Ff + k0 + c0, &sB[l1]);
        __syncthreads();
        short8 af[4];
#pragma unroll
        for (int i = 0; i < 4; i++)
            af[i] = *(const short8*)&sA[(wm + i * 16 + lr) * 32 + quad * 8];
#pragma unroll
        for (int j = 0; j < 4; j++) {
            short8 bf = *(const short8*)&sB[(wn + j * 16 + lr) * 32 + quad * 8];
#pragma unroll
            for (int i = 0; i < 4; i++)
                acc[i][j] = __builtin_amdgcn_mfma_f32_16x16x32_bf16(af[i], bf, acc[i][j], 0, 0, 0);
        }
    }
#pragma unroll
    for (int i = 0; i < 4; i++) {
#pragma unroll
        for (int r = 0; r < 4; r++) {
            const int pos = m0 + wm + i * 16 + quad * 4 + r;
            const int tok = rowmap[pos];
            if (tok >= 0) {
#pragma unroll
                for (int j = 0; j < 4; j++)
                    atomicAdd(&out[(size_t)tok * Dd + (n0 + wn + j * 16 + lr)], acc[i][j][r]);
            }
        }
    }
}

extern "C" void kernel_launch(void* const* d_in, const int* in_sizes, int n_in,
                              void* d_out, int out_size, void* d_ws, size_t ws_size,
                              hipStream_t stream) {
    const float* x   = (const float*)d_in[0];
    const float* gw  = (const float*)d_in[1];
    const float* Wg  = (const float*)d_in[2];
    const float* Wu  = (const float*)d_in[3];
    const float* Wd  = (const float*)d_in[4];
    const float* sWg = (const float*)d_in[5];
    const float* sWu = (const float*)d_in[6];
    const float* sWd = (const float*)d_in[7];
    const float* sgw = (const float*)d_in[8];
    float* out = (float*)d_out;

    // workspace layout (bytes)
    char* ws = (char*)d_ws;
    unsigned short* xb  = (unsigned short*)(ws);                 //  8,388,608  x bf16 [T][D]
    unsigned short* WgT = (unsigned short*)(ws + 8388608);       // 35,651,584  [NE][F][D]
    unsigned short* WuT = (unsigned short*)(ws + 44040192);      // 35,651,584  [NE][F][D]
    unsigned short* WdT = (unsigned short*)(ws + 79691776);      // 35,651,584  [NE][D][F]
    unsigned short* Hp  = (unsigned short*)(ws + 115343360);     // 35,651,584  packed [MAXROWS][F]
    float* comb   = (float*)(ws + 150994944);                    //    139,264  [T][NE]
    int* selids   = (int*)(ws + 151134208);                      //     32,768  [T][4]
    int* counts   = (int*)(ws + 151166976);                      //         64
    int* off      = (int*)(ws + 151167040);                      //        128 (17 used)
    int* cursor   = (int*)(ws + 151167168);                      //         64
    int* meta     = (int*)(ws + 151167232);                      //         64
    int* blocktab = (int*)(ws + 151167296);                      //      1,152 (272 used)
    int* rowmap   = (int*)(ws + 151168448);                      //    139,264 [MAXROWS]

    cast_x_kernel<<<4096, 256, 0, stream>>>(x, xb);
    // Wg/Wu: src [D][F] -> dst [F][D] per expert
    transpose_cast<<<dim3(16, 64, 17), 256, 0, stream>>>(Wg, sWg, WgT, Dd, Ff, (size_t)Ff * Dd, Dd);
    transpose_cast<<<dim3(16, 64, 17), 256, 0, stream>>>(Wu, sWu, WuT, Dd, Ff, (size_t)Ff * Dd, Dd);
    // Wd: src [F][D] -> dst [D][F] per expert
    transpose_cast<<<dim3(64, 16, 17), 256, 0, stream>>>(Wd, sWd, WdT, Ff, Dd, (size_t)Dd * Ff, Ff);
    hipMemsetAsync(counts, 0, 64, stream);
    router_kernel<<<Tt, 64, 0, stream>>>(x, gw, sgw, comb, selids, counts);
    offsets_kernel<<<1, 1, 0, stream>>>(counts, off, cursor, blocktab, meta);
    hipMemsetAsync(rowmap, 0xFF, MAXROWS * sizeof(int), stream);
    scatter_kernel<<<8, 256, 0, stream>>>(selids, off, cursor, rowmap);
    gemm1_kernel<<<dim3(4, MAXTILES), 256, 0, stream>>>(xb, WgT, WuT, comb, rowmap, blocktab, meta, Hp);
    hipMemsetAsync(out, 0, (size_t)Tt * Dd * sizeof(float), stream);
    gemm2_kernel<<<dim3(16, MAXTILES), 256, 0, stream>>>(Hp, WdT, rowmap, blocktab, meta, out);
}

// Round 3
// 544.254 us; speedup vs baseline: 1.2322x; 1.1747x over previous
//
#include <hip/hip_runtime.h>
#include <hip/hip_bf16.h>

#define Tt 2048
#define Dd 2048
#define Ff 512
#define Ee 16
#define NE 17                    // 16 routed experts + 1 shared
#define MAXROWS (NE * Tt)        // 34816 worst-case padded packed rows
#define MAXTILES (MAXROWS / 128) // 272

typedef __attribute__((ext_vector_type(8))) short short8;
typedef __attribute__((ext_vector_type(8))) unsigned short ushort8v;
typedef __attribute__((ext_vector_type(4))) float floatx4;

#define AS1 __attribute__((address_space(1)))
#define AS3 __attribute__((address_space(3)))

__device__ __forceinline__ unsigned short f2bf(float f) {
    union { float f; unsigned u; } v; v.f = f;
    unsigned r = v.u + 0x7FFFu + ((v.u >> 16) & 1u);   // RNE
    return (unsigned short)(r >> 16);
}

__device__ __forceinline__ void gld16(const unsigned short* g, unsigned short* l) {
    __builtin_amdgcn_global_load_lds((const AS1 void*)g, (AS3 void*)l, 16, 0, 0);
}

// ---------------- transpose+cast weights ----------------
// dst[c * dstStride + r] = bf16(src[r * C + c]), src per expert z (z==16 -> shared)
__global__ void transpose_cast(const float* __restrict__ Wsrc, const float* __restrict__ Ssrc,
                               unsigned short* __restrict__ dst, int R, int C,
                               size_t dstEOff, int dstStride) {
    __shared__ float tile[32][33];
    int z = blockIdx.z;
    const float* src = (z < Ee) ? (Wsrc + (size_t)z * R * C) : Ssrc;
    unsigned short* d = dst + (size_t)z * dstEOff;
    int c0 = blockIdx.x * 32;
    int r0 = blockIdx.y * 32;
    int tx = threadIdx.x & 31, ty = threadIdx.x >> 5;   // 32 x 8
#pragma unroll
    for (int i = 0; i < 4; i++) {
        int r = r0 + ty + i * 8;
        tile[ty + i * 8][tx] = src[(size_t)r * C + c0 + tx];
    }
    __syncthreads();
#pragma unroll
    for (int i = 0; i < 4; i++) {
        int c = c0 + ty + i * 8;
        d[(size_t)c * dstStride + r0 + tx] = f2bf(tile[tx][ty + i * 8]);
    }
}

// ---------------- router: logits + softmax + top4 + shared gate + x->bf16 cast ----------------
// One token per block, 256 threads (4 waves). Each thread owns 8 x-elements.
__global__ __launch_bounds__(256) void router_kernel(
    const float* __restrict__ x, const float* __restrict__ gw,
    const float* __restrict__ sgw, float* __restrict__ comb,
    int* __restrict__ selids, int* __restrict__ counts,
    unsigned short* __restrict__ xb)
{
    const int t = blockIdx.x;
    const int tid = threadIdx.x;
    const int lane = tid & 63, wv = tid >> 6;
    const float* xp = x + (size_t)t * Dd + tid * 8;

    float xr[8];
    *(floatx4*)&xr[0] = *(const floatx4*)(xp);
    *(floatx4*)&xr[4] = *(const floatx4*)(xp + 4);

    // fused cast: write bf16 row
    {
        ushort8v o;
#pragma unroll
        for (int j = 0; j < 8; j++) o[j] = f2bf(xr[j]);
        *(ushort8v*)(xb + (size_t)t * Dd + tid * 8) = o;
    }

    float part[NE + 1];
#pragma unroll
    for (int e = 0; e < Ee; e++) {
        const float* g = gw + (size_t)e * Dd + tid * 8;
        floatx4 g0 = *(const floatx4*)(g);
        floatx4 g1 = *(const floatx4*)(g + 4);
        float s = xr[0] * g0.x + xr[1] * g0.y + xr[2] * g0.z + xr[3] * g0.w
                + xr[4] * g1.x + xr[5] * g1.y + xr[6] * g1.z + xr[7] * g1.w;
        part[e] = s;
    }
    {
        const float* g = sgw + tid * 8;
        floatx4 g0 = *(const floatx4*)(g);
        floatx4 g1 = *(const floatx4*)(g + 4);
        part[Ee] = xr[0] * g0.x + xr[1] * g0.y + xr[2] * g0.z + xr[3] * g0.w
                 + xr[4] * g1.x + xr[5] * g1.y + xr[6] * g1.z + xr[7] * g1.w;
    }
    // wave reduce each of the 18 partials
#pragma unroll
    for (int e = 0; e < NE + 1; e++) {
        float s = part[e];
        s += __shfl_xor(s, 32); s += __shfl_xor(s, 16); s += __shfl_xor(s, 8);
        s += __shfl_xor(s, 4);  s += __shfl_xor(s, 2);  s += __shfl_xor(s, 1);
        part[e] = s;
    }
    __shared__ float red[4][NE + 1];
    if (lane == 0) {
#pragma unroll
        for (int e = 0; e < NE + 1; e++) red[wv][e] = part[e];
    }
    __syncthreads();
    if (tid == 0) {
        float lg[NE + 1];
#pragma unroll
        for (int e = 0; e < NE + 1; e++)
            lg[e] = red[0][e] + red[1][e] + red[2][e] + red[3][e];
        float mx = lg[0];
        for (int e = 1; e < Ee; e++) mx = fmaxf(mx, lg[e]);
        float p[Ee]; float sum = 0.f;
        for (int e = 0; e < Ee; e++) { p[e] = __expf(lg[e] - mx); sum += p[e]; }
        float inv = 1.f / sum;
        for (int e = 0; e < Ee; e++) p[e] *= inv;
        bool sel[Ee];
        for (int e = 0; e < Ee; e++) sel[e] = false;
        int ids[4];
        float ssum = 0.f;
        for (int k = 0; k < 4; k++) {
            int bi = 0; float bv = -1.f;
            for (int e = 0; e < Ee; e++)
                if (!sel[e] && p[e] > bv) { bv = p[e]; bi = e; }
            sel[bi] = true; ids[k] = bi; ssum += bv;
        }
        float rinv = 1.f / ssum;
        for (int e = 0; e < Ee; e++) comb[t * NE + e] = sel[e] ? p[e] * rinv : 0.f;
        comb[t * NE + Ee] = 1.f / (1.f + __expf(-lg[Ee]));
        for (int k = 0; k < 4; k++) {
            selids[t * 4 + k] = ids[k];
            atomicAdd(&counts[ids[k]], 1);
        }
    }
}

// ---------------- offsets: tile-padded exclusive scan + block table ----------------
__global__ void offsets_kernel(const int* __restrict__ counts, int* __restrict__ off,
                               int* __restrict__ cursor, int* __restrict__ blocktab,
                               int* __restrict__ meta) {
    int acc = 0, nt = 0;
    for (int e = 0; e < NE; e++) {
        int c = (e < Ee) ? counts[e] : Tt;
        off[e] = acc;
        if (e < Ee) cursor[e] = 0;
        int tiles = (c + 127) >> 7;
        for (int tl = 0; tl < tiles; tl++) blocktab[nt++] = (e << 20) | (acc + tl * 128);
        acc += tiles << 7;
    }
    meta[0] = nt;
}

// ---------------- scatter: build rowmap (packed position -> token) ----------------
__global__ void scatter_kernel(const int* __restrict__ selids, const int* __restrict__ off,
                               int* __restrict__ cursor, int* __restrict__ rowmap) {
    int t = blockIdx.x * 256 + threadIdx.x;
    if (t >= Tt) return;
#pragma unroll
    for (int k = 0; k < 4; k++) {
        int e = selids[t * 4 + k];
        int r = atomicAdd(&cursor[e], 1);
        rowmap[off[e] + r] = t;
    }
    rowmap[off[Ee] + t] = t;    // shared expert: identity
}

// ---------------- GEMM1: Hp[pos][f] = comb * silu(x@Wg_e) * (x@Wu_e), grouped ----------------
__global__ __launch_bounds__(256, 2) void gemm1_kernel(
    const unsigned short* __restrict__ xb,
    const unsigned short* __restrict__ WgT,
    const unsigned short* __restrict__ WuT,
    const float* __restrict__ comb,
    const int* __restrict__ rowmap,
    const int* __restrict__ blocktab,
    const int* __restrict__ meta,
    unsigned short* __restrict__ Hp)
{
    if ((int)blockIdx.y >= meta[0]) return;
    __shared__ unsigned short sA[128 * 32];
    __shared__ unsigned short sG[128 * 32];
    __shared__ unsigned short sU[128 * 32];
    const int info = blocktab[blockIdx.y];
    const int e  = info >> 20;
    const int m0 = info & 0xFFFFF;
    const int n0 = blockIdx.x * 128;
    const int tid = threadIdx.x;
    const int lane = tid & 63, wv = tid >> 6;
    const int wm = (wv >> 1) * 64, wn = (wv & 1) * 64;
    const int lr = lane & 15, quad = lane >> 4;

    const unsigned short* Gb = WgT + (size_t)e * Ff * Dd + (size_t)n0 * Dd;
    const unsigned short* Ub = WuT + (size_t)e * Ff * Dd + (size_t)n0 * Dd;

    const int l0 = tid * 8;                 // element offset in [128][32] tile
    const int r0 = l0 >> 5, c0 = l0 & 31;
    const int l1 = l0 + 2048;
    const int r1 = r0 + 64;

    // indirect A rows (padded slots -> token 0, weight forced to 0 in epilogue)
    const int tk0 = rowmap[m0 + r0];
    const int tk1 = rowmap[m0 + r1];
    const unsigned short* a0 = xb + (size_t)(tk0 < 0 ? 0 : tk0) * Dd + c0;
    const unsigned short* a1 = xb + (size_t)(tk1 < 0 ? 0 : tk1) * Dd + c0;

    floatx4 accg[4][4], accu[4][4];
#pragma unroll
    for (int i = 0; i < 4; i++)
#pragma unroll
        for (int j = 0; j < 4; j++) {
            accg[i][j] = (floatx4){0.f, 0.f, 0.f, 0.f};
            accu[i][j] = (floatx4){0.f, 0.f, 0.f, 0.f};
        }

    for (int k0 = 0; k0 < Dd; k0 += 32) {
        __syncthreads();
        gld16(a0 + k0, &sA[l0]);
        gld16(a1 + k0, &sA[l1]);
        gld16(Gb + (size_t)r0 * Dd + k0 + c0, &sG[l0]);
        gld16(Gb + (size_t)r1 * Dd + k0 + c0, &sG[l1]);
        gld16(Ub + (size_t)r0 * Dd + k0 + c0, &sU[l0]);
        gld16(Ub + (size_t)r1 * Dd + k0 + c0, &sU[l1]);
        __syncthreads();
        short8 af[4];
#pragma unroll
        for (int i = 0; i < 4; i++)
            af[i] = *(const short8*)&sA[(wm + i * 16 + lr) * 32 + quad * 8];
#pragma unroll
        for (int j = 0; j < 4; j++) {
            short8 bg = *(const short8*)&sG[(wn + j * 16 + lr) * 32 + quad * 8];
            short8 bu = *(const short8*)&sU[(wn + j * 16 + lr) * 32 + quad * 8];
#pragma unroll
            for (int i = 0; i < 4; i++) {
                accg[i][j] = __builtin_amdgcn_mfma_f32_16x16x32_bf16(af[i], bg, accg[i][j], 0, 0, 0);
                accu[i][j] = __builtin_amdgcn_mfma_f32_16x16x32_bf16(af[i], bu, accu[i][j], 0, 0, 0);
            }
        }
    }
    // epilogue: C/D layout col=lane&15, row=quad*4+reg
#pragma unroll
    for (int i = 0; i < 4; i++) {
#pragma unroll
        for (int r = 0; r < 4; r++) {
            const int pos = m0 + wm + i * 16 + quad * 4 + r;
            const int tok = rowmap[pos];
            const float wc = (tok >= 0) ? comb[tok * NE + e] : 0.f;
#pragma unroll
            for (int j = 0; j < 4; j++) {
                const float g = accg[i][j][r];
                const float u = accu[i][j][r];
                const float h = (g / (1.f + __expf(-g))) * u * wc;
                Hp[(size_t)pos * Ff + (n0 + wn + j * 16 + lr)] = f2bf(h);
            }
        }
    }
}

// ---------------- GEMM2: out[tok] += Hp[pos] @ Wd_e, grouped, scatter-atomic ----------------
__global__ __launch_bounds__(256, 2) void gemm2_kernel(
    const unsigned short* __restrict__ Hp,
    const unsigned short* __restrict__ WdT,   // [NE][D][F]  (B^T per expert)
    const int* __restrict__ rowmap,
    const int* __restrict__ blocktab,
    const int* __restrict__ meta,
    float* __restrict__ out)
{
    if ((int)blockIdx.y >= meta[0]) return;
    __shared__ unsigned short sA[128 * 32];
    __shared__ unsigned short sB[128 * 32];
    const int info = blocktab[blockIdx.y];
    const int e  = info >> 20;
    const int m0 = info & 0xFFFFF;
    const int n0 = blockIdx.x * 128;
    const int tid = threadIdx.x;
    const int lane = tid & 63, wv = tid >> 6;
    const int wm = (wv >> 1) * 64, wn = (wv & 1) * 64;
    const int lr = lane & 15, quad = lane >> 4;

    const unsigned short* Ab = Hp + (size_t)m0 * Ff;
    const unsigned short* Bb = WdT + (size_t)e * Dd * Ff + (size_t)n0 * Ff;

    const int l0 = tid * 8;
    const int r0 = l0 >> 5, c0 = l0 & 31;
    const int l1 = l0 + 2048;
    const int r1 = r0 + 64;

    floatx4 acc[4][4];
#pragma unroll
    for (int i = 0; i < 4; i++)
#pragma unroll
        for (int j = 0; j < 4; j++) acc[i][j] = (floatx4){0.f, 0.f, 0.f, 0.f};

    for (int k0 = 0; k0 < Ff; k0 += 32) {
        __syncthreads();
        gld16(Ab + (size_t)r0 * Ff + k0 + c0, &sA[l0]);
        gld16(Ab + (size_t)r1 * Ff + k0 + c0, &sA[l1]);
        gld16(Bb + (size_t)r0 * Ff + k0 + c0, &sB[l0]);
        gld16(Bb + (size_t)r1 * Ff + k0 + c0, &sB[l1]);
        __syncthreads();
        short8 af[4];
#pragma unroll
        for (int i = 0; i < 4; i++)
            af[i] = *(const short8*)&sA[(wm + i * 16 + lr) * 32 + quad * 8];
#pragma unroll
        for (int j = 0; j < 4; j++) {
            short8 bf = *(const short8*)&sB[(wn + j * 16 + lr) * 32 + quad * 8];
#pragma unroll
            for (int i = 0; i < 4; i++)
                acc[i][j] = __builtin_amdgcn_mfma_f32_16x16x32_bf16(af[i], bf, acc[i][j], 0, 0, 0);
        }
    }
#pragma unroll
    for (int i = 0; i < 4; i++) {
#pragma unroll
        for (int r = 0; r < 4; r++) {
            const int pos = m0 + wm + i * 16 + quad * 4 + r;
            const int tok = rowmap[pos];
            if (tok >= 0) {
#pragma unroll
                for (int j = 0; j < 4; j++)
                    atomicAdd(&out[(size_t)tok * Dd + (n0 + wn + j * 16 + lr)], acc[i][j][r]);
            }
        }
    }
}

extern "C" void kernel_launch(void* const* d_in, const int* in_sizes, int n_in,
                              void* d_out, int out_size, void* d_ws, size_t ws_size,
                              hipStream_t stream) {
    const float* x   = (const float*)d_in[0];
    const float* gw  = (const float*)d_in[1];
    const float* Wg  = (const float*)d_in[2];
    const float* Wu  = (const float*)d_in[3];
    const float* Wd  = (const float*)d_in[4];
    const float* sWg = (const float*)d_in[5];
    const float* sWu = (const float*)d_in[6];
    const float* sWd = (const float*)d_in[7];
    const float* sgw = (const float*)d_in[8];
    float* out = (float*)d_out;

    // workspace layout (bytes)
    char* ws = (char*)d_ws;
    unsigned short* xb  = (unsigned short*)(ws);                 //  8,388,608  x bf16 [T][D]
    unsigned short* WgT = (unsigned short*)(ws + 8388608);       // 35,651,584  [NE][F][D]
    unsigned short* WuT = (unsigned short*)(ws + 44040192);      // 35,651,584  [NE][F][D]
    unsigned short* WdT = (unsigned short*)(ws + 79691776);      // 35,651,584  [NE][D][F]
    unsigned short* Hp  = (unsigned short*)(ws + 115343360);     // 35,651,584  packed [MAXROWS][F]
    float* comb   = (float*)(ws + 150994944);                    //    139,264  [T][NE]
    int* selids   = (int*)(ws + 151134208);                      //     32,768  [T][4]
    int* counts   = (int*)(ws + 151166976);                      //         64
    int* off      = (int*)(ws + 151167040);                      //        128 (17 used)
    int* cursor   = (int*)(ws + 151167168);                      //         64
    int* meta     = (int*)(ws + 151167232);                      //         64
    int* blocktab = (int*)(ws + 151167296);                      //      1,152 (272 used)
    int* rowmap   = (int*)(ws + 151168448);                      //    139,264 [MAXROWS]

    // Wg/Wu: src [D][F] -> dst [F][D] per expert
    transpose_cast<<<dim3(16, 64, 17), 256, 0, stream>>>(Wg, sWg, WgT, Dd, Ff, (size_t)Ff * Dd, Dd);
    transpose_cast<<<dim3(16, 64, 17), 256, 0, stream>>>(Wu, sWu, WuT, Dd, Ff, (size_t)Ff * Dd, Dd);
    // Wd: src [F][D] -> dst [D][F] per expert
    transpose_cast<<<dim3(64, 16, 17), 256, 0, stream>>>(Wd, sWd, WdT, Ff, Dd, (size_t)Dd * Ff, Ff);
    hipMemsetAsync(counts, 0, 64, stream);
    router_kernel<<<Tt, 256, 0, stream>>>(x, gw, sgw, comb, selids, counts, xb);
    offsets_kernel<<<1, 1, 0, stream>>>(counts, off, cursor, blocktab, meta);
    hipMemsetAsync(rowmap, 0xFF, MAXROWS * sizeof(int), stream);
    scatter_kernel<<<8, 256, 0, stream>>>(selids, off, cursor, rowmap);
    gemm1_kernel<<<dim3(4, MAXTILES), 256, 0, stream>>>(xb, WgT, WuT, comb, rowmap, blocktab, meta, Hp);
    hipMemsetAsync(out, 0, (size_t)Tt * Dd * sizeof(float), stream);
    gemm2_kernel<<<dim3(16, MAXTILES), 256, 0, stream>>>(Hp, WdT, rowmap, blocktab, meta, out);
}

// Round 4
// 492.089 us; speedup vs baseline: 1.3628x; 1.1060x over previous
//
#include <hip/hip_runtime.h>
#include <hip/hip_bf16.h>

#define Tt 2048
#define Dd 2048
#define Ff 512
#define Ee 16
#define NE 17                    // 16 routed experts + 1 shared
#define MAXROWS 12288            // sum_e ceil(c_e/128)*128 (<=8192+16*127 -> 10224, pad) + 2048 shared
#define MAXTILES 96

typedef __attribute__((ext_vector_type(8))) short short8;
typedef __attribute__((ext_vector_type(8))) unsigned short ushort8v;
typedef __attribute__((ext_vector_type(4))) float floatx4;

#define AS1 __attribute__((address_space(1)))
#define AS3 __attribute__((address_space(3)))

__device__ __forceinline__ unsigned short f2bf(float f) {
    union { float f; unsigned u; } v; v.f = f;
    unsigned r = v.u + 0x7FFFu + ((v.u >> 16) & 1u);   // RNE
    return (unsigned short)(r >> 16);
}
__device__ __forceinline__ float bf2f(unsigned short h) {
    union { unsigned u; float f; } v; v.u = ((unsigned)h) << 16;
    return v.f;
}

__device__ __forceinline__ void gld16(const unsigned short* g, unsigned short* l) {
    __builtin_amdgcn_global_load_lds((const AS1 void*)g, (AS3 void*)l, 16, 0, 0);
}

// ---------------- split-cast x -> bf16 hi + bf16 lo ----------------
__global__ void splitcast_x(const float* __restrict__ x, unsigned short* __restrict__ xh,
                            unsigned short* __restrict__ xl) {
    int i = (blockIdx.x * 256 + threadIdx.x) * 8;
    float v[8];
    *(floatx4*)&v[0] = *(const floatx4*)(x + i);
    *(floatx4*)&v[4] = *(const floatx4*)(x + i + 4);
    ushort8v h, l;
#pragma unroll
    for (int j = 0; j < 8; j++) {
        unsigned short hb = f2bf(v[j]);
        h[j] = hb;
        l[j] = f2bf(v[j] - bf2f(hb));
    }
    *(ushort8v*)(xh + i) = h;
    *(ushort8v*)(xl + i) = l;
}

// ---------------- split gate weights into gB[2][32][2048] (hi,lo), rows 17..31 zero ----------------
__global__ void splitg_kernel(const float* __restrict__ gw, const float* __restrict__ sgw,
                              unsigned short* __restrict__ gB) {
    int z = blockIdx.x;                // 0..31
    int i = threadIdx.x * 8;
    ushort8v h = {0,0,0,0,0,0,0,0}, l = {0,0,0,0,0,0,0,0};
    if (z < NE) {
        const float* src = (z < Ee) ? (gw + (size_t)z * Dd) : sgw;
        float v[8];
        *(floatx4*)&v[0] = *(const floatx4*)(src + i);
        *(floatx4*)&v[4] = *(const floatx4*)(src + i + 4);
#pragma unroll
        for (int j = 0; j < 8; j++) {
            unsigned short hb = f2bf(v[j]);
            h[j] = hb;
            l[j] = f2bf(v[j] - bf2f(hb));
        }
    }
    *(ushort8v*)(gB + (size_t)z * Dd + i) = h;
    *(ushort8v*)(gB + 32 * Dd + (size_t)z * Dd + i) = l;
}

// ---------------- logits GEMM: part[kb][t][n] = sum_k x*gw (hi/lo compensated) ----------------
// M=2048, N=32, K=2048 split into 8 chunks of 256. 128-token tile, 4 waves each 32 rows.
__global__ __launch_bounds__(256) void logits_kernel(
    const unsigned short* __restrict__ xh, const unsigned short* __restrict__ xl,
    const unsigned short* __restrict__ gB, float* __restrict__ part) {
    __shared__ unsigned short sAh[128 * 32];
    __shared__ unsigned short sAl[128 * 32];
    __shared__ unsigned short sB[2048];     // [0..1023] hi 32x32, [1024..2047] lo 32x32
    const int m0 = blockIdx.x * 128;
    const int kb = blockIdx.y;
    const int k00 = kb * 256;
    const int tid = threadIdx.x;
    const int lane = tid & 63, wv = tid >> 6;
    const int lr = lane & 15, quad = lane >> 4;

    const int l0 = tid * 8;
    const int r0 = l0 >> 5, c0 = l0 & 31;
    const int l1 = l0 + 2048;
    const int r1 = r0 + 64;
    // B staging: tid<128 -> hi plane, else lo plane
    const int br = (tid >> 2) & 31, bc = (tid & 3) * 8;
    const unsigned short* bsrc = gB + ((tid >= 128) ? 32 * Dd : 0) + (size_t)br * Dd + bc;

    floatx4 acc[2][2];
#pragma unroll
    for (int i = 0; i < 2; i++)
#pragma unroll
        for (int j = 0; j < 2; j++) acc[i][j] = (floatx4){0.f, 0.f, 0.f, 0.f};

    for (int kk = 0; kk < 256; kk += 32) {
        __syncthreads();
        gld16(xh + (size_t)(m0 + r0) * Dd + k00 + kk + c0, &sAh[l0]);
        gld16(xh + (size_t)(m0 + r1) * Dd + k00 + kk + c0, &sAh[l1]);
        gld16(xl + (size_t)(m0 + r0) * Dd + k00 + kk + c0, &sAl[l0]);
        gld16(xl + (size_t)(m0 + r1) * Dd + k00 + kk + c0, &sAl[l1]);
        gld16(bsrc + k00 + kk, &sB[l0 & 2047]);
        __syncthreads();
#pragma unroll
        for (int mi = 0; mi < 2; mi++) {
            const int ar = wv * 32 + mi * 16 + lr;
            short8 ah = *(const short8*)&sAh[ar * 32 + quad * 8];
            short8 al = *(const short8*)&sAl[ar * 32 + quad * 8];
#pragma unroll
            for (int nj = 0; nj < 2; nj++) {
                short8 bh = *(const short8*)&sB[(nj * 16 + lr) * 32 + quad * 8];
                short8 bl = *(const short8*)&sB[1024 + (nj * 16 + lr) * 32 + quad * 8];
                acc[mi][nj] = __builtin_amdgcn_mfma_f32_16x16x32_bf16(ah, bh, acc[mi][nj], 0, 0, 0);
                acc[mi][nj] = __builtin_amdgcn_mfma_f32_16x16x32_bf16(ah, bl, acc[mi][nj], 0, 0, 0);
                acc[mi][nj] = __builtin_amdgcn_mfma_f32_16x16x32_bf16(al, bh, acc[mi][nj], 0, 0, 0);
            }
        }
    }
#pragma unroll
    for (int mi = 0; mi < 2; mi++)
#pragma unroll
        for (int r = 0; r < 4; r++) {
            const int t = m0 + wv * 32 + mi * 16 + quad * 4 + r;
#pragma unroll
            for (int nj = 0; nj < 2; nj++)
                part[((size_t)kb * Tt + t) * 32 + nj * 16 + lr] = acc[mi][nj][r];
        }
}

// ---------------- topk: reduce split-K partials, softmax, top4, shared gate ----------------
__global__ void topk_kernel(const float* __restrict__ part, float* __restrict__ comb,
                            int* __restrict__ selids, int* __restrict__ counts) {
    const int t = blockIdx.x * 64 + threadIdx.x;
    float lg[20];
#pragma unroll
    for (int j = 0; j < 20; j++) lg[j] = 0.f;
#pragma unroll
    for (int kb = 0; kb < 8; kb++) {
        const float* p = part + ((size_t)kb * Tt + t) * 32;
#pragma unroll
        for (int q = 0; q < 5; q++) {
            floatx4 a = *(const floatx4*)(p + q * 4);
            lg[q * 4 + 0] += a.x; lg[q * 4 + 1] += a.y;
            lg[q * 4 + 2] += a.z; lg[q * 4 + 3] += a.w;
        }
    }
    float mx = lg[0];
    for (int e = 1; e < Ee; e++) mx = fmaxf(mx, lg[e]);
    float p[Ee]; float sum = 0.f;
    for (int e = 0; e < Ee; e++) { p[e] = __expf(lg[e] - mx); sum += p[e]; }
    float inv = 1.f / sum;
    for (int e = 0; e < Ee; e++) p[e] *= inv;
    bool sel[Ee];
    for (int e = 0; e < Ee; e++) sel[e] = false;
    int ids[4];
    float ssum = 0.f;
    for (int k = 0; k < 4; k++) {
        int bi = 0; float bv = -1.f;
        for (int e = 0; e < Ee; e++)
            if (!sel[e] && p[e] > bv) { bv = p[e]; bi = e; }
        sel[bi] = true; ids[k] = bi; ssum += bv;
    }
    float rinv = 1.f / ssum;
    for (int e = 0; e < Ee; e++) comb[t * NE + e] = sel[e] ? p[e] * rinv : 0.f;
    comb[t * NE + Ee] = 1.f / (1.f + __expf(-lg[16]));
#pragma unroll
    for (int k = 0; k < 4; k++) {
        selids[t * 4 + k] = ids[k];
        atomicAdd(&counts[ids[k]], 1);
    }
}

// ---------------- transpose+cast v2: 64x64 tile, 4x4 register micro-transpose ----------------
// dst[c * dstStride + r] = bf16(src[r * C + c]); expert z (z==16 -> shared)
__global__ void transpose_cast(const float* __restrict__ Wsrc, const float* __restrict__ Ssrc,
                               unsigned short* __restrict__ dst, int R, int C,
                               size_t dstEOff, int dstStride) {
    int z = blockIdx.z;
    const float* src = (z < Ee) ? (Wsrc + (size_t)z * R * C) : Ssrc;
    unsigned short* d = dst + (size_t)z * dstEOff;
    const int c = blockIdx.x * 64 + (threadIdx.x & 15) * 4;
    const int r = blockIdx.y * 64 + (threadIdx.x >> 4) * 4;
    floatx4 v[4];
#pragma unroll
    for (int i = 0; i < 4; i++)
        v[i] = *(const floatx4*)(src + (size_t)(r + i) * C + c);
#pragma unroll
    for (int j = 0; j < 4; j++) {
        ushort4 w;
        w.x = f2bf(v[0][j]); w.y = f2bf(v[1][j]);
        w.z = f2bf(v[2][j]); w.w = f2bf(v[3][j]);
        *(ushort4*)(d + (size_t)(c + j) * dstStride + r) = w;
    }
}

// ---------------- offsets: tile-padded exclusive scan + block table ----------------
__global__ void offsets_kernel(const int* __restrict__ counts, int* __restrict__ off,
                               int* __restrict__ cursor, int* __restrict__ blocktab,
                               int* __restrict__ meta) {
    int acc = 0, nt = 0;
    for (int e = 0; e < NE; e++) {
        int c = (e < Ee) ? counts[e] : Tt;
        off[e] = acc;
        if (e < Ee) cursor[e] = 0;
        int tiles = (c + 127) >> 7;
        for (int tl = 0; tl < tiles; tl++) blocktab[nt++] = (e << 20) | (acc + tl * 128);
        acc += tiles << 7;
    }
    meta[0] = nt;
}

// ---------------- scatter: build rowmap (packed position -> token) ----------------
__global__ void scatter_kernel(const int* __restrict__ selids, const int* __restrict__ off,
                               int* __restrict__ cursor, int* __restrict__ rowmap) {
    int t = blockIdx.x * 256 + threadIdx.x;
    if (t >= Tt) return;
#pragma unroll
    for (int k = 0; k < 4; k++) {
        int e = selids[t * 4 + k];
        int r = atomicAdd(&cursor[e], 1);
        rowmap[off[e] + r] = t;
    }
    rowmap[off[Ee] + t] = t;    // shared expert: identity
}

// ---------------- GEMM1: Hp[pos][f] = comb * silu(x@Wg_e) * (x@Wu_e), grouped ----------------
__global__ __launch_bounds__(256, 2) void gemm1_kernel(
    const unsigned short* __restrict__ xb,
    const unsigned short* __restrict__ WgT,
    const unsigned short* __restrict__ WuT,
    const float* __restrict__ comb,
    const int* __restrict__ rowmap,
    const int* __restrict__ blocktab,
    const int* __restrict__ meta,
    unsigned short* __restrict__ Hp)
{
    if ((int)blockIdx.y >= meta[0]) return;
    __shared__ unsigned short sA[128 * 32];
    __shared__ unsigned short sG[128 * 32];
    __shared__ unsigned short sU[128 * 32];
    const int info = blocktab[blockIdx.y];
    const int e  = info >> 20;
    const int m0 = info & 0xFFFFF;
    const int n0 = blockIdx.x * 128;
    const int tid = threadIdx.x;
    const int lane = tid & 63, wv = tid >> 6;
    const int wm = (wv >> 1) * 64, wn = (wv & 1) * 64;
    const int lr = lane & 15, quad = lane >> 4;

    const unsigned short* Gb = WgT + (size_t)e * Ff * Dd + (size_t)n0 * Dd;
    const unsigned short* Ub = WuT + (size_t)e * Ff * Dd + (size_t)n0 * Dd;

    const int l0 = tid * 8;                 // element offset in [128][32] tile
    const int r0 = l0 >> 5, c0 = l0 & 31;
    const int l1 = l0 + 2048;
    const int r1 = r0 + 64;

    const int tk0 = rowmap[m0 + r0];
    const int tk1 = rowmap[m0 + r1];
    const unsigned short* a0 = xb + (size_t)(tk0 < 0 ? 0 : tk0) * Dd + c0;
    const unsigned short* a1 = xb + (size_t)(tk1 < 0 ? 0 : tk1) * Dd + c0;

    floatx4 accg[4][4], accu[4][4];
#pragma unroll
    for (int i = 0; i < 4; i++)
#pragma unroll
        for (int j = 0; j < 4; j++) {
            accg[i][j] = (floatx4){0.f, 0.f, 0.f, 0.f};
            accu[i][j] = (floatx4){0.f, 0.f, 0.f, 0.f};
        }

    for (int k0 = 0; k0 < Dd; k0 += 32) {
        __syncthreads();
        gld16(a0 + k0, &sA[l0]);
        gld16(a1 + k0, &sA[l1]);
        gld16(Gb + (size_t)r0 * Dd + k0 + c0, &sG[l0]);
        gld16(Gb + (size_t)r1 * Dd + k0 + c0, &sG[l1]);
        gld16(Ub + (size_t)r0 * Dd + k0 + c0, &sU[l0]);
        gld16(Ub + (size_t)r1 * Dd + k0 + c0, &sU[l1]);
        __syncthreads();
        short8 af[4];
#pragma unroll
        for (int i = 0; i < 4; i++)
            af[i] = *(const short8*)&sA[(wm + i * 16 + lr) * 32 + quad * 8];
#pragma unroll
        for (int j = 0; j < 4; j++) {
            short8 bg = *(const short8*)&sG[(wn + j * 16 + lr) * 32 + quad * 8];
            short8 bu = *(const short8*)&sU[(wn + j * 16 + lr) * 32 + quad * 8];
#pragma unroll
            for (int i = 0; i < 4; i++) {
                accg[i][j] = __builtin_amdgcn_mfma_f32_16x16x32_bf16(af[i], bg, accg[i][j], 0, 0, 0);
                accu[i][j] = __builtin_amdgcn_mfma_f32_16x16x32_bf16(af[i], bu, accu[i][j], 0, 0, 0);
            }
        }
    }
#pragma unroll
    for (int i = 0; i < 4; i++) {
#pragma unroll
        for (int r = 0; r < 4; r++) {
            const int pos = m0 + wm + i * 16 + quad * 4 + r;
            const int tok = rowmap[pos];
            const float wc = (tok >= 0) ? comb[tok * NE + e] : 0.f;
#pragma unroll
            for (int j = 0; j < 4; j++) {
                const float g = accg[i][j][r];
                const float u = accu[i][j][r];
                const float h = (g / (1.f + __expf(-g))) * u * wc;
                Hp[(size_t)pos * Ff + (n0 + wn + j * 16 + lr)] = f2bf(h);
            }
        }
    }
}

// ---------------- GEMM2: out[tok] += Hp[pos] @ Wd_e, grouped, scatter-atomic ----------------
__global__ __launch_bounds__(256, 2) void gemm2_kernel(
    const unsigned short* __restrict__ Hp,
    const unsigned short* __restrict__ WdT,   // [NE][D][F]  (B^T per expert)
    const int* __restrict__ rowmap,
    const int* __restrict__ blocktab,
    const int* __restrict__ meta,
    float* __restrict__ out)
{
    if ((int)blockIdx.y >= meta[0]) return;
    __shared__ unsigned short sA[128 * 32];
    __shared__ unsigned short sB[128 * 32];
    const int info = blocktab[blockIdx.y];
    const int e  = info >> 20;
    const int m0 = info & 0xFFFFF;
    const int n0 = blockIdx.x * 128;
    const int tid = threadIdx.x;
    const int lane = tid & 63, wv = tid >> 6;
    const int wm = (wv >> 1) * 64, wn = (wv & 1) * 64;
    const int lr = lane & 15, quad = lane >> 4;

    const unsigned short* Ab = Hp + (size_t)m0 * Ff;
    const unsigned short* Bb = WdT + (size_t)e * Dd * Ff + (size_t)n0 * Ff;

    const int l0 = tid * 8;
    const int r0 = l0 >> 5, c0 = l0 & 31;
    const int l1 = l0 + 2048;
    const int r1 = r0 + 64;

    floatx4 acc[4][4];
#pragma unroll
    for (int i = 0; i < 4; i++)
#pragma unroll
        for (int j = 0; j < 4; j++) acc[i][j] = (floatx4){0.f, 0.f, 0.f, 0.f};

    for (int k0 = 0; k0 < Ff; k0 += 32) {
        __syncthreads();
        gld16(Ab + (size_t)r0 * Ff + k0 + c0, &sA[l0]);
        gld16(Ab + (size_t)r1 * Ff + k0 + c0, &sA[l1]);
        gld16(Bb + (size_t)r0 * Ff + k0 + c0, &sB[l0]);
        gld16(Bb + (size_t)r1 * Ff + k0 + c0, &sB[l1]);
        __syncthreads();
        short8 af[4];
#pragma unroll
        for (int i = 0; i < 4; i++)
            af[i] = *(const short8*)&sA[(wm + i * 16 + lr) * 32 + quad * 8];
#pragma unroll
        for (int j = 0; j < 4; j++) {
            short8 bf = *(const short8*)&sB[(wn + j * 16 + lr) * 32 + quad * 8];
#pragma unroll
            for (int i = 0; i < 4; i++)
                acc[i][j] = __builtin_amdgcn_mfma_f32_16x16x32_bf16(af[i], bf, acc[i][j], 0, 0, 0);
        }
    }
#pragma unroll
    for (int i = 0; i < 4; i++) {
#pragma unroll
        for (int r = 0; r < 4; r++) {
            const int pos = m0 + wm + i * 16 + quad * 4 + r;
            const int tok = rowmap[pos];
            if (tok >= 0) {
#pragma unroll
                for (int j = 0; j < 4; j++)
                    atomicAdd(&out[(size_t)tok * Dd + (n0 + wn + j * 16 + lr)], acc[i][j][r]);
            }
        }
    }
}

extern "C" void kernel_launch(void* const* d_in, const int* in_sizes, int n_in,
                              void* d_out, int out_size, void* d_ws, size_t ws_size,
                              hipStream_t stream) {
    const float* x   = (const float*)d_in[0];
    const float* gw  = (const float*)d_in[1];
    const float* Wg  = (const float*)d_in[2];
    const float* Wu  = (const float*)d_in[3];
    const float* Wd  = (const float*)d_in[4];
    const float* sWg = (const float*)d_in[5];
    const float* sWu = (const float*)d_in[6];
    const float* sWd = (const float*)d_in[7];
    const float* sgw = (const float*)d_in[8];
    float* out = (float*)d_out;

    // workspace layout (bytes)
    char* ws = (char*)d_ws;
    unsigned short* xb   = (unsigned short*)(ws);                //  8,388,608  x bf16 hi [T][D]
    unsigned short* xl   = (unsigned short*)(ws + 8388608);      //  8,388,608  x bf16 lo [T][D]
    unsigned short* WgT  = (unsigned short*)(ws + 16777216);     // 35,651,584  [NE][F][D]
    unsigned short* WuT  = (unsigned short*)(ws + 52428800);     // 35,651,584  [NE][F][D]
    unsigned short* WdT  = (unsigned short*)(ws + 88080384);     // 35,651,584  [NE][D][F]
    unsigned short* Hp   = (unsigned short*)(ws + 123731968);    // 12,582,912  packed [MAXROWS][F]
    float* part    = (float*)(ws + 136314880);                   //  2,097,152  [8][T][32]
    unsigned short* gB   = (unsigned short*)(ws + 138412032);    //    262,144  [2][32][D]
    float* comb    = (float*)(ws + 138674176);                   //    139,264  [T][NE]
    int* selids    = (int*)(ws + 138813440);                     //     32,768  [T][4]
    int* counts    = (int*)(ws + 138846208);                     //         64
    int* off       = (int*)(ws + 138846272);                     //        128
    int* cursor    = (int*)(ws + 138846400);                     //         64
    int* meta      = (int*)(ws + 138846464);                     //         64
    int* blocktab  = (int*)(ws + 138846528);                     //        512
    int* rowmap    = (int*)(ws + 138847040);                     //     49,152 [MAXROWS]

    // Wg/Wu: src [D][F] -> dst [F][D] per expert ; Wd: src [F][D] -> dst [D][F]
    transpose_cast<<<dim3(Ff / 64, Dd / 64, 17), 256, 0, stream>>>(Wg, sWg, WgT, Dd, Ff, (size_t)Ff * Dd, Dd);
    transpose_cast<<<dim3(Ff / 64, Dd / 64, 17), 256, 0, stream>>>(Wu, sWu, WuT, Dd, Ff, (size_t)Ff * Dd, Dd);
    transpose_cast<<<dim3(Dd / 64, Ff / 64, 17), 256, 0, stream>>>(Wd, sWd, WdT, Ff, Dd, (size_t)Dd * Ff, Ff);

    splitcast_x<<<Tt * Dd / 2048, 256, 0, stream>>>(x, xb, xl);
    splitg_kernel<<<32, 256, 0, stream>>>(gw, sgw, gB);
    logits_kernel<<<dim3(Tt / 128, 8), 256, 0, stream>>>(xb, xl, gB, part);
    hipMemsetAsync(counts, 0, 64, stream);
    topk_kernel<<<Tt / 64, 64, 0, stream>>>(part, comb, selids, counts);
    offsets_kernel<<<1, 1, 0, stream>>>(counts, off, cursor, blocktab, meta);
    hipMemsetAsync(rowmap, 0xFF, MAXROWS * sizeof(int), stream);
    scatter_kernel<<<8, 256, 0, stream>>>(selids, off, cursor, rowmap);
    gemm1_kernel<<<dim3(4, MAXTILES), 256, 0, stream>>>(xb, WgT, WuT, comb, rowmap, blocktab, meta, Hp);
    hipMemsetAsync(out, 0, (size_t)Tt * Dd * sizeof(float), stream);
    gemm2_kernel<<<dim3(16, MAXTILES), 256, 0, stream>>>(Hp, WdT, rowmap, blocktab, meta, out);
}

// Round 5
// 437.074 us; speedup vs baseline: 1.5343x; 1.1259x over previous
//
#include <hip/hip_runtime.h>
#include <hip/hip_bf16.h>

#define Tt 2048
#define Dd 2048
#define Ff 512
#define Ee 16
#define NE 17                    // 16 routed experts + 1 shared
#define MAXROWS 12288            // sum_e ceil(c_e/128)*128 + 2048 shared, padded
#define MAXTILES 96

typedef __attribute__((ext_vector_type(8))) short short8;
typedef __attribute__((ext_vector_type(8))) unsigned short ushort8v;
typedef __attribute__((ext_vector_type(4))) float floatx4;

#define AS1 __attribute__((address_space(1)))
#define AS3 __attribute__((address_space(3)))

__device__ __forceinline__ unsigned short f2bf(float f) {
    union { float f; unsigned u; } v; v.f = f;
    unsigned r = v.u + 0x7FFFu + ((v.u >> 16) & 1u);   // RNE
    return (unsigned short)(r >> 16);
}
__device__ __forceinline__ float bf2f(unsigned short h) {
    union { unsigned u; float f; } v; v.u = ((unsigned)h) << 16;
    return v.f;
}

__device__ __forceinline__ void gld16(const unsigned short* g, unsigned short* l) {
    __builtin_amdgcn_global_load_lds((const AS1 void*)g, (AS3 void*)l, 16, 0, 0);
}

// ---------------- split-cast x -> bf16 hi + bf16 lo ----------------
__global__ void splitcast_x(const float* __restrict__ x, unsigned short* __restrict__ xh,
                            unsigned short* __restrict__ xl) {
    int i = (blockIdx.x * 256 + threadIdx.x) * 8;
    float v[8];
    *(floatx4*)&v[0] = *(const floatx4*)(x + i);
    *(floatx4*)&v[4] = *(const floatx4*)(x + i + 4);
    ushort8v h, l;
#pragma unroll
    for (int j = 0; j < 8; j++) {
        unsigned short hb = f2bf(v[j]);
        h[j] = hb;
        l[j] = f2bf(v[j] - bf2f(hb));
    }
    *(ushort8v*)(xh + i) = h;
    *(ushort8v*)(xl + i) = l;
}

// ---------------- split gate weights into gB[2][32][2048] (hi,lo), rows 17..31 zero ----------------
__global__ void splitg_kernel(const float* __restrict__ gw, const float* __restrict__ sgw,
                              unsigned short* __restrict__ gB) {
    int z = blockIdx.x;                // 0..31
    int i = threadIdx.x * 8;
    ushort8v h = {0,0,0,0,0,0,0,0}, l = {0,0,0,0,0,0,0,0};
    if (z < NE) {
        const float* src = (z < Ee) ? (gw + (size_t)z * Dd) : sgw;
        float v[8];
        *(floatx4*)&v[0] = *(const floatx4*)(src + i);
        *(floatx4*)&v[4] = *(const floatx4*)(src + i + 4);
#pragma unroll
        for (int j = 0; j < 8; j++) {
            unsigned short hb = f2bf(v[j]);
            h[j] = hb;
            l[j] = f2bf(v[j] - bf2f(hb));
        }
    }
    *(ushort8v*)(gB + (size_t)z * Dd + i) = h;
    *(ushort8v*)(gB + 32 * Dd + (size_t)z * Dd + i) = l;
}

// ---------------- logits GEMM: part[kb][t][n] = sum_k x*gw (hi/lo compensated) ----------------
__global__ __launch_bounds__(256) void logits_kernel(
    const unsigned short* __restrict__ xh, const unsigned short* __restrict__ xl,
    const unsigned short* __restrict__ gB, float* __restrict__ part) {
    __shared__ unsigned short sAh[128 * 32];
    __shared__ unsigned short sAl[128 * 32];
    __shared__ unsigned short sB[2048];     // [0..1023] hi 32x32, [1024..2047] lo 32x32
    const int m0 = blockIdx.x * 128;
    const int kb = blockIdx.y;
    const int k00 = kb * 256;
    const int tid = threadIdx.x;
    const int lane = tid & 63, wv = tid >> 6;
    const int lr = lane & 15, quad = lane >> 4;

    const int l0 = tid * 8;
    const int r0 = l0 >> 5, c0 = l0 & 31;
    const int l1 = l0 + 2048;
    const int r1 = r0 + 64;
    const int br = (tid >> 2) & 31, bc = (tid & 3) * 8;
    const unsigned short* bsrc = gB + ((tid >= 128) ? 32 * Dd : 0) + (size_t)br * Dd + bc;

    floatx4 acc[2][2];
#pragma unroll
    for (int i = 0; i < 2; i++)
#pragma unroll
        for (int j = 0; j < 2; j++) acc[i][j] = (floatx4){0.f, 0.f, 0.f, 0.f};

    for (int kk = 0; kk < 256; kk += 32) {
        __syncthreads();
        gld16(xh + (size_t)(m0 + r0) * Dd + k00 + kk + c0, &sAh[l0]);
        gld16(xh + (size_t)(m0 + r1) * Dd + k00 + kk + c0, &sAh[l1]);
        gld16(xl + (size_t)(m0 + r0) * Dd + k00 + kk + c0, &sAl[l0]);
        gld16(xl + (size_t)(m0 + r1) * Dd + k00 + kk + c0, &sAl[l1]);
        gld16(bsrc + k00 + kk, &sB[l0 & 2047]);
        __syncthreads();
#pragma unroll
        for (int mi = 0; mi < 2; mi++) {
            const int ar = wv * 32 + mi * 16 + lr;
            short8 ah = *(const short8*)&sAh[ar * 32 + quad * 8];
            short8 al = *(const short8*)&sAl[ar * 32 + quad * 8];
#pragma unroll
            for (int nj = 0; nj < 2; nj++) {
                short8 bh = *(const short8*)&sB[(nj * 16 + lr) * 32 + quad * 8];
                short8 bl = *(const short8*)&sB[1024 + (nj * 16 + lr) * 32 + quad * 8];
                acc[mi][nj] = __builtin_amdgcn_mfma_f32_16x16x32_bf16(ah, bh, acc[mi][nj], 0, 0, 0);
                acc[mi][nj] = __builtin_amdgcn_mfma_f32_16x16x32_bf16(ah, bl, acc[mi][nj], 0, 0, 0);
                acc[mi][nj] = __builtin_amdgcn_mfma_f32_16x16x32_bf16(al, bh, acc[mi][nj], 0, 0, 0);
            }
        }
    }
#pragma unroll
    for (int mi = 0; mi < 2; mi++)
#pragma unroll
        for (int r = 0; r < 4; r++) {
            const int t = m0 + wv * 32 + mi * 16 + quad * 4 + r;
#pragma unroll
            for (int nj = 0; nj < 2; nj++)
                part[((size_t)kb * Tt + t) * 32 + nj * 16 + lr] = acc[mi][nj][r];
        }
}

// ---------------- topk: reduce split-K partials, softmax, top4, shared gate ----------------
__global__ void topk_kernel(const float* __restrict__ part, float* __restrict__ comb,
                            int* __restrict__ selids, int* __restrict__ counts) {
    const int t = blockIdx.x * 64 + threadIdx.x;
    float lg[20];
#pragma unroll
    for (int j = 0; j < 20; j++) lg[j] = 0.f;
#pragma unroll
    for (int kb = 0; kb < 8; kb++) {
        const float* p = part + ((size_t)kb * Tt + t) * 32;
#pragma unroll
        for (int q = 0; q < 5; q++) {
            floatx4 a = *(const floatx4*)(p + q * 4);
            lg[q * 4 + 0] += a.x; lg[q * 4 + 1] += a.y;
            lg[q * 4 + 2] += a.z; lg[q * 4 + 3] += a.w;
        }
    }
    float mx = lg[0];
    for (int e = 1; e < Ee; e++) mx = fmaxf(mx, lg[e]);
    float p[Ee]; float sum = 0.f;
    for (int e = 0; e < Ee; e++) { p[e] = __expf(lg[e] - mx); sum += p[e]; }
    float inv = 1.f / sum;
    for (int e = 0; e < Ee; e++) p[e] *= inv;
    bool sel[Ee];
    for (int e = 0; e < Ee; e++) sel[e] = false;
    int ids[4];
    float ssum = 0.f;
    for (int k = 0; k < 4; k++) {
        int bi = 0; float bv = -1.f;
        for (int e = 0; e < Ee; e++)
            if (!sel[e] && p[e] > bv) { bv = p[e]; bi = e; }
        sel[bi] = true; ids[k] = bi; ssum += bv;
    }
    float rinv = 1.f / ssum;
    for (int e = 0; e < Ee; e++) comb[t * NE + e] = sel[e] ? p[e] * rinv : 0.f;
    comb[t * NE + Ee] = 1.f / (1.f + __expf(-lg[16]));
#pragma unroll
    for (int k = 0; k < 4; k++) {
        selids[t * 4 + k] = ids[k];
        atomicAdd(&counts[ids[k]], 1);
    }
}

// ---------------- transpose+cast v3: 64x64 tile via LDS, coalesced both sides ----------------
// dst[c * dstStride + r] = bf16(src[r * C + c]); expert z (z==16 -> shared)
__global__ void transpose_cast(const float* __restrict__ Wsrc, const float* __restrict__ Ssrc,
                               unsigned short* __restrict__ dst, int R, int C,
                               size_t dstEOff, int dstStride) {
    __shared__ unsigned short lt[64 * 68];      // [c][r], stride 68 (8B-aligned rows)
    int z = blockIdx.z;
    const float* src = (z < Ee) ? (Wsrc + (size_t)z * R * C) : Ssrc;
    unsigned short* d = dst + (size_t)z * dstEOff;
    const int c0 = blockIdx.x * 64, r0 = blockIdx.y * 64;
    const int tx = threadIdx.x & 15, ty = threadIdx.x >> 4;   // 16 x 16
#pragma unroll
    for (int i = 0; i < 4; i++) {
        const int r = ty + i * 16;
        floatx4 v = *(const floatx4*)(src + (size_t)(r0 + r) * C + c0 + tx * 4);
#pragma unroll
        for (int j = 0; j < 4; j++) lt[(tx * 4 + j) * 68 + r] = f2bf(v[j]);
    }
    __syncthreads();
#pragma unroll
    for (int i = 0; i < 4; i++) {
        const int cc = ty + i * 16;
        ushort4 w = *(const ushort4*)&lt[cc * 68 + tx * 4];
        *(ushort4*)(d + (size_t)(c0 + cc) * dstStride + r0 + tx * 4) = w;
    }
}

// ---------------- offsets: tile-padded exclusive scan + block table ----------------
__global__ void offsets_kernel(const int* __restrict__ counts, int* __restrict__ off,
                               int* __restrict__ cursor, int* __restrict__ blocktab,
                               int* __restrict__ meta) {
    int acc = 0, nt = 0;
    for (int e = 0; e < NE; e++) {
        int c = (e < Ee) ? counts[e] : Tt;
        off[e] = acc;
        if (e < Ee) cursor[e] = 0;
        int tiles = (c + 127) >> 7;
        for (int tl = 0; tl < tiles; tl++) blocktab[nt++] = (e << 20) | (acc + tl * 128);
        acc += tiles << 7;
    }
    meta[0] = nt;
}

// ---------------- scatter: rowmap (pos -> token) + tokpos (token -> its 5 positions) ----------------
__global__ void scatter_kernel(const int* __restrict__ selids, const int* __restrict__ off,
                               int* __restrict__ cursor, int* __restrict__ rowmap,
                               int* __restrict__ tokpos) {
    int t = blockIdx.x * 256 + threadIdx.x;
    if (t >= Tt) return;
#pragma unroll
    for (int k = 0; k < 4; k++) {
        int e = selids[t * 4 + k];
        int r = atomicAdd(&cursor[e], 1);
        int pos = off[e] + r;
        rowmap[pos] = t;
        tokpos[t * 8 + k] = pos;
    }
    int sp = off[Ee] + t;
    rowmap[sp] = t;            // shared expert: identity
    tokpos[t * 8 + 4] = sp;
}

// ---------------- GEMM1: Hp[pos][f] = comb * silu(x@Wg_e) * (x@Wu_e), grouped ----------------
__global__ __launch_bounds__(256, 2) void gemm1_kernel(
    const unsigned short* __restrict__ xb,
    const unsigned short* __restrict__ WgT,
    const unsigned short* __restrict__ WuT,
    const float* __restrict__ comb,
    const int* __restrict__ rowmap,
    const int* __restrict__ blocktab,
    const int* __restrict__ meta,
    unsigned short* __restrict__ Hp)
{
    if ((int)blockIdx.y >= meta[0]) return;
    __shared__ unsigned short sA[128 * 32];
    __shared__ unsigned short sG[128 * 32];
    __shared__ unsigned short sU[128 * 32];
    const int info = blocktab[blockIdx.y];
    const int e  = info >> 20;
    const int m0 = info & 0xFFFFF;
    const int n0 = blockIdx.x * 128;
    const int tid = threadIdx.x;
    const int lane = tid & 63, wv = tid >> 6;
    const int wm = (wv >> 1) * 64, wn = (wv & 1) * 64;
    const int lr = lane & 15, quad = lane >> 4;

    const unsigned short* Gb = WgT + (size_t)e * Ff * Dd + (size_t)n0 * Dd;
    const unsigned short* Ub = WuT + (size_t)e * Ff * Dd + (size_t)n0 * Dd;

    const int l0 = tid * 8;                 // element offset in [128][32] tile
    const int r0 = l0 >> 5, c0 = l0 & 31;
    const int l1 = l0 + 2048;
    const int r1 = r0 + 64;

    const int tk0 = rowmap[m0 + r0];
    const int tk1 = rowmap[m0 + r1];
    const unsigned short* a0 = xb + (size_t)(tk0 < 0 ? 0 : tk0) * Dd + c0;
    const unsigned short* a1 = xb + (size_t)(tk1 < 0 ? 0 : tk1) * Dd + c0;

    floatx4 accg[4][4], accu[4][4];
#pragma unroll
    for (int i = 0; i < 4; i++)
#pragma unroll
        for (int j = 0; j < 4; j++) {
            accg[i][j] = (floatx4){0.f, 0.f, 0.f, 0.f};
            accu[i][j] = (floatx4){0.f, 0.f, 0.f, 0.f};
        }

    for (int k0 = 0; k0 < Dd; k0 += 32) {
        __syncthreads();
        gld16(a0 + k0, &sA[l0]);
        gld16(a1 + k0, &sA[l1]);
        gld16(Gb + (size_t)r0 * Dd + k0 + c0, &sG[l0]);
        gld16(Gb + (size_t)r1 * Dd + k0 + c0, &sG[l1]);
        gld16(Ub + (size_t)r0 * Dd + k0 + c0, &sU[l0]);
        gld16(Ub + (size_t)r1 * Dd + k0 + c0, &sU[l1]);
        __syncthreads();
        short8 af[4];
#pragma unroll
        for (int i = 0; i < 4; i++)
            af[i] = *(const short8*)&sA[(wm + i * 16 + lr) * 32 + quad * 8];
#pragma unroll
        for (int j = 0; j < 4; j++) {
            short8 bg = *(const short8*)&sG[(wn + j * 16 + lr) * 32 + quad * 8];
            short8 bu = *(const short8*)&sU[(wn + j * 16 + lr) * 32 + quad * 8];
#pragma unroll
            for (int i = 0; i < 4; i++) {
                accg[i][j] = __builtin_amdgcn_mfma_f32_16x16x32_bf16(af[i], bg, accg[i][j], 0, 0, 0);
                accu[i][j] = __builtin_amdgcn_mfma_f32_16x16x32_bf16(af[i], bu, accu[i][j], 0, 0, 0);
            }
        }
    }
#pragma unroll
    for (int i = 0; i < 4; i++) {
#pragma unroll
        for (int r = 0; r < 4; r++) {
            const int pos = m0 + wm + i * 16 + quad * 4 + r;
            const int tok = rowmap[pos];
            const float wc = (tok >= 0) ? comb[tok * NE + e] : 0.f;
#pragma unroll
            for (int j = 0; j < 4; j++) {
                const float g = accg[i][j][r];
                const float u = accu[i][j][r];
                const float h = (g / (1.f + __expf(-g))) * u * wc;
                Hp[(size_t)pos * Ff + (n0 + wn + j * 16 + lr)] = f2bf(h);
            }
        }
    }
}

// ---------------- GEMM2: Op[pos] = Hp[pos] @ Wd_e (packed bf16, plain stores) ----------------
__global__ __launch_bounds__(256, 2) void gemm2_kernel(
    const unsigned short* __restrict__ Hp,
    const unsigned short* __restrict__ WdT,   // [NE][D][F]  (B^T per expert)
    const int* __restrict__ blocktab,
    const int* __restrict__ meta,
    unsigned short* __restrict__ Op)          // [MAXROWS][D] bf16 packed
{
    if ((int)blockIdx.y >= meta[0]) return;
    __shared__ unsigned short sMem[128 * 32 * 2];   // sA | sB, reused for epilogue
    unsigned short* sA = sMem;
    unsigned short* sB = sMem + 4096;
    const int info = blocktab[blockIdx.y];
    const int e  = info >> 20;
    const int m0 = info & 0xFFFFF;
    const int n0 = blockIdx.x * 128;
    const int tid = threadIdx.x;
    const int lane = tid & 63, wv = tid >> 6;
    const int wm = (wv >> 1) * 64, wn = (wv & 1) * 64;
    const int lr = lane & 15, quad = lane >> 4;

    const unsigned short* Ab = Hp + (size_t)m0 * Ff;
    const unsigned short* Bb = WdT + (size_t)e * Dd * Ff + (size_t)n0 * Ff;

    const int l0 = tid * 8;
    const int r0 = l0 >> 5, c0 = l0 & 31;
    const int l1 = l0 + 2048;
    const int r1 = r0 + 64;

    floatx4 acc[4][4];
#pragma unroll
    for (int i = 0; i < 4; i++)
#pragma unroll
        for (int j = 0; j < 4; j++) acc[i][j] = (floatx4){0.f, 0.f, 0.f, 0.f};

    for (int k0 = 0; k0 < Ff; k0 += 32) {
        __syncthreads();
        gld16(Ab + (size_t)r0 * Ff + k0 + c0, &sA[l0]);
        gld16(Ab + (size_t)r1 * Ff + k0 + c0, &sA[l1]);
        gld16(Bb + (size_t)r0 * Ff + k0 + c0, &sB[l0]);
        gld16(Bb + (size_t)r1 * Ff + k0 + c0, &sB[l1]);
        __syncthreads();
        short8 af[4];
#pragma unroll
        for (int i = 0; i < 4; i++)
            af[i] = *(const short8*)&sA[(wm + i * 16 + lr) * 32 + quad * 8];
#pragma unroll
        for (int j = 0; j < 4; j++) {
            short8 bf = *(const short8*)&sB[(wn + j * 16 + lr) * 32 + quad * 8];
#pragma unroll
            for (int i = 0; i < 4; i++)
                acc[i][j] = __builtin_amdgcn_mfma_f32_16x16x32_bf16(af[i], bf, acc[i][j], 0, 0, 0);
        }
    }
    // epilogue: per-wave 64x64 bf16 tile staged through LDS, coalesced ushort8 stores
    unsigned short* sOut = sMem + wv * 2048;        // 4 KB per wave (32 rows x 64 cols)
    __syncthreads();                                // K-loop LDS reads done
#pragma unroll
    for (int h = 0; h < 2; h++) {
#pragma unroll
        for (int ii = 0; ii < 2; ii++) {
            const int i = h * 2 + ii;
#pragma unroll
            for (int r = 0; r < 4; r++) {
                const int lrow = ii * 16 + quad * 4 + r;
#pragma unroll
                for (int j = 0; j < 4; j++)
                    sOut[lrow * 64 + j * 16 + lr] = f2bf(acc[i][j][r]);
            }
        }
        __syncthreads();
        const int prow0 = m0 + wm + h * 32;
#pragma unroll
        for (int it = 0; it < 4; it++) {
            const int idx = it * 512 + lane * 8;
            const int row = idx >> 6, col = idx & 63;
            ushort8v vv = *(const ushort8v*)&sOut[row * 64 + col];
            *(ushort8v*)&Op[(size_t)(prow0 + row) * Dd + n0 + wn + col] = vv;
        }
        __syncthreads();
    }
}

// ---------------- reduce: out[t] = sum of the token's 5 packed Op rows ----------------
__global__ __launch_bounds__(256) void reduce_kernel(
    const unsigned short* __restrict__ Op, const int* __restrict__ tokpos,
    float* __restrict__ out)
{
    const int t = blockIdx.x;
    const int c = threadIdx.x * 8;
    int ps[5];
#pragma unroll
    for (int k = 0; k < 5; k++) ps[k] = tokpos[t * 8 + k];
    float s[8];
#pragma unroll
    for (int j = 0; j < 8; j++) s[j] = 0.f;
#pragma unroll
    for (int k = 0; k < 5; k++) {
        ushort8v v = *(const ushort8v*)&Op[(size_t)ps[k] * Dd + c];
#pragma unroll
        for (int j = 0; j < 8; j++) s[j] += bf2f(v[j]);
    }
    *(floatx4*)(out + (size_t)t * Dd + c) = *(floatx4*)&s[0];
    *(floatx4*)(out + (size_t)t * Dd + c + 4) = *(floatx4*)&s[4];
}

extern "C" void kernel_launch(void* const* d_in, const int* in_sizes, int n_in,
                              void* d_out, int out_size, void* d_ws, size_t ws_size,
                              hipStream_t stream) {
    const float* x   = (const float*)d_in[0];
    const float* gw  = (const float*)d_in[1];
    const float* Wg  = (const float*)d_in[2];
    const float* Wu  = (const float*)d_in[3];
    const float* Wd  = (const float*)d_in[4];
    const float* sWg = (const float*)d_in[5];
    const float* sWu = (const float*)d_in[6];
    const float* sWd = (const float*)d_in[7];
    const float* sgw = (const float*)d_in[8];
    float* out = (float*)d_out;

    // workspace layout (bytes)
    char* ws = (char*)d_ws;
    unsigned short* xb   = (unsigned short*)(ws);                //  8,388,608  x bf16 hi [T][D]
    unsigned short* xl   = (unsigned short*)(ws + 8388608);      //  8,388,608  x bf16 lo [T][D]
    unsigned short* WgT  = (unsigned short*)(ws + 16777216);     // 35,651,584  [NE][F][D]
    unsigned short* WuT  = (unsigned short*)(ws + 52428800);     // 35,651,584  [NE][F][D]
    unsigned short* Op   = (unsigned short*)(ws + 16777216);     // 50,331,648  [MAXROWS][D] (aliases WgT/WuT, used after gemm1)
    unsigned short* WdT  = (unsigned short*)(ws + 88080384);     // 35,651,584  [NE][D][F]
    unsigned short* Hp   = (unsigned short*)(ws + 123731968);    // 12,582,912  packed [MAXROWS][F]
    float* part    = (float*)(ws + 136314880);                   //  2,097,152  [8][T][32]
    unsigned short* gB   = (unsigned short*)(ws + 138412032);    //    262,144  [2][32][D]
    float* comb    = (float*)(ws + 138674176);                   //    139,264  [T][NE]
    int* selids    = (int*)(ws + 138813440);                     //     32,768  [T][4]
    int* counts    = (int*)(ws + 138846208);                     //         64
    int* off       = (int*)(ws + 138846272);                     //        128
    int* cursor    = (int*)(ws + 138846400);                     //         64
    int* meta      = (int*)(ws + 138846464);                     //         64
    int* blocktab  = (int*)(ws + 138846528);                     //        512
    int* rowmap    = (int*)(ws + 138847040);                     //     49,152 [MAXROWS]
    int* tokpos    = (int*)(ws + 138896192);                     //     65,536 [T][8]

    // Wg/Wu: src [D][F] -> dst [F][D] per expert ; Wd: src [F][D] -> dst [D][F]
    transpose_cast<<<dim3(Ff / 64, Dd / 64, 17), 256, 0, stream>>>(Wg, sWg, WgT, Dd, Ff, (size_t)Ff * Dd, Dd);
    transpose_cast<<<dim3(Ff / 64, Dd / 64, 17), 256, 0, stream>>>(Wu, sWu, WuT, Dd, Ff, (size_t)Ff * Dd, Dd);
    transpose_cast<<<dim3(Dd / 64, Ff / 64, 17), 256, 0, stream>>>(Wd, sWd, WdT, Ff, Dd, (size_t)Dd * Ff, Ff);

    splitcast_x<<<Tt * Dd / 2048, 256, 0, stream>>>(x, xb, xl);
    splitg_kernel<<<32, 256, 0, stream>>>(gw, sgw, gB);
    logits_kernel<<<dim3(Tt / 128, 8), 256, 0, stream>>>(xb, xl, gB, part);
    hipMemsetAsync(counts, 0, 64, stream);
    topk_kernel<<<Tt / 64, 64, 0, stream>>>(part, comb, selids, counts);
    offsets_kernel<<<1, 1, 0, stream>>>(counts, off, cursor, blocktab, meta);
    hipMemsetAsync(rowmap, 0xFF, MAXROWS * sizeof(int), stream);
    scatter_kernel<<<8, 256, 0, stream>>>(selids, off, cursor, rowmap, tokpos);
    gemm1_kernel<<<dim3(4, MAXTILES), 256, 0, stream>>>(xb, WgT, WuT, comb, rowmap, blocktab, meta, Hp);
    gemm2_kernel<<<dim3(16, MAXTILES), 256, 0, stream>>>(Hp, WdT, blocktab, meta, Op);
    reduce_kernel<<<Tt, 256, 0, stream>>>(Op, tokpos, out);
}

// Round 6
// 412.516 us; speedup vs baseline: 1.6257x; 1.0595x over previous
//
#include <hip/hip_runtime.h>
#include <hip/hip_bf16.h>

#define Tt 2048
#define Dd 2048
#define Ff 512
#define Ee 16
#define NE 17                    // 16 routed experts + 1 shared
#define MAXROWS 12288            // 80 routed tiles*128 + 16 shared tiles*128
#define MAXTILES 96

typedef __attribute__((ext_vector_type(8))) short short8;
typedef __attribute__((ext_vector_type(8))) unsigned short ushort8v;
typedef __attribute__((ext_vector_type(4))) float floatx4;

#define AS1 __attribute__((address_space(1)))
#define AS3 __attribute__((address_space(3)))

__device__ __forceinline__ unsigned short f2bf(float f) {
    union { float f; unsigned u; } v; v.f = f;
    unsigned r = v.u + 0x7FFFu + ((v.u >> 16) & 1u);   // RNE
    return (unsigned short)(r >> 16);
}
__device__ __forceinline__ float bf2f(unsigned short h) {
    union { unsigned u; float f; } v; v.u = ((unsigned)h) << 16;
    return v.f;
}

__device__ __forceinline__ void gld16(const unsigned short* g, unsigned short* l) {
    __builtin_amdgcn_global_load_lds((const AS1 void*)g, (AS3 void*)l, 16, 0, 0);
}

// ---------------- split-cast x -> bf16 hi + bf16 lo ----------------
__global__ void splitcast_x(const float* __restrict__ x, unsigned short* __restrict__ xh,
                            unsigned short* __restrict__ xl) {
    int i = (blockIdx.x * 256 + threadIdx.x) * 8;
    float v[8];
    *(floatx4*)&v[0] = *(const floatx4*)(x + i);
    *(floatx4*)&v[4] = *(const floatx4*)(x + i + 4);
    ushort8v h, l;
#pragma unroll
    for (int j = 0; j < 8; j++) {
        unsigned short hb = f2bf(v[j]);
        h[j] = hb;
        l[j] = f2bf(v[j] - bf2f(hb));
    }
    *(ushort8v*)(xh + i) = h;
    *(ushort8v*)(xl + i) = l;
}

// ---------------- split gate weights into gB[2][32][2048] (hi,lo), rows 17..31 zero ----------------
__global__ void splitg_kernel(const float* __restrict__ gw, const float* __restrict__ sgw,
                              unsigned short* __restrict__ gB) {
    int z = blockIdx.x;                // 0..31
    int i = threadIdx.x * 8;
    ushort8v h = {0,0,0,0,0,0,0,0}, l = {0,0,0,0,0,0,0,0};
    if (z < NE) {
        const float* src = (z < Ee) ? (gw + (size_t)z * Dd) : sgw;
        float v[8];
        *(floatx4*)&v[0] = *(const floatx4*)(src + i);
        *(floatx4*)&v[4] = *(const floatx4*)(src + i + 4);
#pragma unroll
        for (int j = 0; j < 8; j++) {
            unsigned short hb = f2bf(v[j]);
            h[j] = hb;
            l[j] = f2bf(v[j] - bf2f(hb));
        }
    }
    *(ushort8v*)(gB + (size_t)z * Dd + i) = h;
    *(ushort8v*)(gB + 32 * Dd + (size_t)z * Dd + i) = l;
}

// ---------------- logits GEMM: part[kb][t][n] = sum_k x*gw (hi/lo compensated) ----------------
__global__ __launch_bounds__(256) void logits_kernel(
    const unsigned short* __restrict__ xh, const unsigned short* __restrict__ xl,
    const unsigned short* __restrict__ gB, float* __restrict__ part) {
    __shared__ unsigned short sAh[128 * 32];
    __shared__ unsigned short sAl[128 * 32];
    __shared__ unsigned short sB[2048];     // [0..1023] hi 32x32, [1024..2047] lo 32x32
    const int m0 = blockIdx.x * 128;
    const int kb = blockIdx.y;
    const int k00 = kb * 256;
    const int tid = threadIdx.x;
    const int lane = tid & 63, wv = tid >> 6;
    const int lr = lane & 15, quad = lane >> 4;

    const int l0 = tid * 8;
    const int r0 = l0 >> 5, c0 = l0 & 31;
    const int l1 = l0 + 2048;
    const int r1 = r0 + 64;
    const int br = (tid >> 2) & 31, bc = (tid & 3) * 8;
    const unsigned short* bsrc = gB + ((tid >= 128) ? 32 * Dd : 0) + (size_t)br * Dd + bc;

    floatx4 acc[2][2];
#pragma unroll
    for (int i = 0; i < 2; i++)
#pragma unroll
        for (int j = 0; j < 2; j++) acc[i][j] = (floatx4){0.f, 0.f, 0.f, 0.f};

    for (int kk = 0; kk < 256; kk += 32) {
        __syncthreads();
        gld16(xh + (size_t)(m0 + r0) * Dd + k00 + kk + c0, &sAh[l0]);
        gld16(xh + (size_t)(m0 + r1) * Dd + k00 + kk + c0, &sAh[l1]);
        gld16(xl + (size_t)(m0 + r0) * Dd + k00 + kk + c0, &sAl[l0]);
        gld16(xl + (size_t)(m0 + r1) * Dd + k00 + kk + c0, &sAl[l1]);
        gld16(bsrc + k00 + kk, &sB[l0 & 2047]);
        __syncthreads();
#pragma unroll
        for (int mi = 0; mi < 2; mi++) {
            const int ar = wv * 32 + mi * 16 + lr;
            short8 ah = *(const short8*)&sAh[ar * 32 + quad * 8];
            short8 al = *(const short8*)&sAl[ar * 32 + quad * 8];
#pragma unroll
            for (int nj = 0; nj < 2; nj++) {
                short8 bh = *(const short8*)&sB[(nj * 16 + lr) * 32 + quad * 8];
                short8 bl = *(const short8*)&sB[1024 + (nj * 16 + lr) * 32 + quad * 8];
                acc[mi][nj] = __builtin_amdgcn_mfma_f32_16x16x32_bf16(ah, bh, acc[mi][nj], 0, 0, 0);
                acc[mi][nj] = __builtin_amdgcn_mfma_f32_16x16x32_bf16(ah, bl, acc[mi][nj], 0, 0, 0);
                acc[mi][nj] = __builtin_amdgcn_mfma_f32_16x16x32_bf16(al, bh, acc[mi][nj], 0, 0, 0);
            }
        }
    }
#pragma unroll
    for (int mi = 0; mi < 2; mi++)
#pragma unroll
        for (int r = 0; r < 4; r++) {
            const int t = m0 + wv * 32 + mi * 16 + quad * 4 + r;
#pragma unroll
            for (int nj = 0; nj < 2; nj++)
                part[((size_t)kb * Tt + t) * 32 + nj * 16 + lr] = acc[mi][nj][r];
        }
}

// ---------------- topk: reduce split-K partials, softmax, top4, shared gate ----------------
__global__ void topk_kernel(const float* __restrict__ part, float* __restrict__ comb,
                            int* __restrict__ selids, int* __restrict__ counts) {
    const int t = blockIdx.x * 64 + threadIdx.x;
    float lg[20];
#pragma unroll
    for (int j = 0; j < 20; j++) lg[j] = 0.f;
#pragma unroll
    for (int kb = 0; kb < 8; kb++) {
        const float* p = part + ((size_t)kb * Tt + t) * 32;
#pragma unroll
        for (int q = 0; q < 5; q++) {
            floatx4 a = *(const floatx4*)(p + q * 4);
            lg[q * 4 + 0] += a.x; lg[q * 4 + 1] += a.y;
            lg[q * 4 + 2] += a.z; lg[q * 4 + 3] += a.w;
        }
    }
    float mx = lg[0];
    for (int e = 1; e < Ee; e++) mx = fmaxf(mx, lg[e]);
    float p[Ee]; float sum = 0.f;
    for (int e = 0; e < Ee; e++) { p[e] = __expf(lg[e] - mx); sum += p[e]; }
    float inv = 1.f / sum;
    for (int e = 0; e < Ee; e++) p[e] *= inv;
    bool sel[Ee];
    for (int e = 0; e < Ee; e++) sel[e] = false;
    int ids[4];
    float ssum = 0.f;
    for (int k = 0; k < 4; k++) {
        int bi = 0; float bv = -1.f;
        for (int e = 0; e < Ee; e++)
            if (!sel[e] && p[e] > bv) { bv = p[e]; bi = e; }
        sel[bi] = true; ids[k] = bi; ssum += bv;
    }
    float rinv = 1.f / ssum;
    for (int e = 0; e < Ee; e++) comb[t * NE + e] = sel[e] ? p[e] * rinv : 0.f;
    comb[t * NE + Ee] = 1.f / (1.f + __expf(-lg[16]));
#pragma unroll
    for (int k = 0; k < 4; k++) {
        selids[t * 4 + k] = ids[k];
        atomicAdd(&counts[ids[k]], 1);
    }
}

// ---------------- offsets: tile-padded exclusive scan + block table ----------------
__global__ void offsets_kernel(const int* __restrict__ counts, int* __restrict__ off,
                               int* __restrict__ cursor, int* __restrict__ blocktab,
                               int* __restrict__ meta) {
    int acc = 0, nt = 0;
    for (int e = 0; e < NE; e++) {
        int c = (e < Ee) ? counts[e] : Tt;
        off[e] = acc;
        if (e < Ee) cursor[e] = 0;
        int tiles = (c + 127) >> 7;
        for (int tl = 0; tl < tiles; tl++) blocktab[nt++] = (e << 20) | (acc + tl * 128);
        acc += tiles << 7;
    }
    meta[0] = nt;
}

// ---------------- scatter: rowmap (pos -> token) + tokpos (token -> its 5 positions) ----------------
__global__ void scatter_kernel(const int* __restrict__ selids, const int* __restrict__ off,
                               int* __restrict__ cursor, int* __restrict__ rowmap,
                               int* __restrict__ tokpos) {
    int t = blockIdx.x * 256 + threadIdx.x;
    if (t >= Tt) return;
#pragma unroll
    for (int k = 0; k < 4; k++) {
        int e = selids[t * 4 + k];
        int r = atomicAdd(&cursor[e], 1);
        int pos = off[e] + r;
        rowmap[pos] = t;
        tokpos[t * 8 + k] = pos;
    }
    int sp = off[Ee] + t;
    rowmap[sp] = t;            // shared expert: identity
    tokpos[t * 8 + 4] = sp;
}

// ---------------- GEMM1: Hp[pos][f] = comb * silu(x@Wg_e) * (x@Wu_e) ----------------
// 128x64 tile. Weights consumed in NATIVE [D][F] fp32 layout: staged via registers,
// bf16-converted, 4x4 micro-transposed into [n][k] LDS (stride 40 = 16B-aligned b128
// reads, decorrelated banks). Next K-tile fp32 prefetched into regs during staging.
__global__ __launch_bounds__(256, 3) void gemm1_kernel(
    const unsigned short* __restrict__ xb,
    const float* __restrict__ Wg, const float* __restrict__ sWg,
    const float* __restrict__ Wu, const float* __restrict__ sWu,
    const float* __restrict__ comb,
    const int* __restrict__ rowmap,
    const int* __restrict__ blocktab,
    const int* __restrict__ meta,
    unsigned short* __restrict__ Hp)
{
    if ((int)blockIdx.y >= meta[0]) return;
    __shared__ unsigned short sA[128 * 32];   // A tile (gld16 lane-contiguous layout)
    __shared__ unsigned short sG[64 * 40];    // B^T tile [n][k], padded stride 40
    __shared__ unsigned short sU[64 * 40];
    const int info = blocktab[blockIdx.y];
    const int e  = info >> 20;
    const int m0 = info & 0xFFFFF;
    const int n0 = blockIdx.x * 64;
    const int tid = threadIdx.x;
    const int lane = tid & 63, wv = tid >> 6;
    const int wm = (wv >> 1) * 64, wn = (wv & 1) * 32;
    const int lr = lane & 15, quad = lane >> 4;

    const float* Gsrc = (e < Ee) ? (Wg + (size_t)e * Dd * Ff) : sWg;
    const float* Usrc = (e < Ee) ? (Wu + (size_t)e * Dd * Ff) : sWu;
    // staging: threads 0..127 stage G, 128..255 stage U; each owns a 4k x 4n block
    const int sx = tid & 15, sy = (tid >> 4) & 7, plane = tid >> 7;
    const float* psrc = (plane ? Usrc : Gsrc) + (size_t)(sy * 4) * Ff + n0 + sx * 4;
    unsigned short* sDst = (plane ? sU : sG) + (sx * 4) * 40 + sy * 4;

    const int l0 = tid * 8;
    const int r0 = l0 >> 5, c0 = l0 & 31;
    const int l1 = l0 + 2048;
    const int r1 = r0 + 64;
    const int tk0 = rowmap[m0 + r0];
    const int tk1 = rowmap[m0 + r1];
    const unsigned short* a0 = xb + (size_t)(tk0 < 0 ? 0 : tk0) * Dd + c0;
    const unsigned short* a1 = xb + (size_t)(tk1 < 0 ? 0 : tk1) * Dd + c0;

    floatx4 pre[4];
#pragma unroll
    for (int i = 0; i < 4; i++) pre[i] = *(const floatx4*)(psrc + (size_t)i * Ff);

    floatx4 accg[4][2], accu[4][2];
#pragma unroll
    for (int i = 0; i < 4; i++)
#pragma unroll
        for (int j = 0; j < 2; j++) {
            accg[i][j] = (floatx4){0.f, 0.f, 0.f, 0.f};
            accu[i][j] = (floatx4){0.f, 0.f, 0.f, 0.f};
        }

    for (int k0 = 0; k0 < Dd; k0 += 32) {
        __syncthreads();
        // convert + micro-transpose write: ushort4 along k at row (sx*4+jj)
#pragma unroll
        for (int jj = 0; jj < 4; jj++) {
            ushort4 w;
            w.x = f2bf(pre[0][jj]); w.y = f2bf(pre[1][jj]);
            w.z = f2bf(pre[2][jj]); w.w = f2bf(pre[3][jj]);
            *(ushort4*)&sDst[jj * 40] = w;
        }
        gld16(a0 + k0, &sA[l0]);
        gld16(a1 + k0, &sA[l1]);
        if (k0 + 32 < Dd) {
            const float* np = psrc + (size_t)(k0 + 32) * Ff;
#pragma unroll
            for (int i = 0; i < 4; i++) pre[i] = *(const floatx4*)(np + (size_t)i * Ff);
        }
        __syncthreads();
        short8 af[4];
#pragma unroll
        for (int i = 0; i < 4; i++)
            af[i] = *(const short8*)&sA[(wm + i * 16 + lr) * 32 + quad * 8];
#pragma unroll
        for (int j = 0; j < 2; j++) {
            short8 bg = *(const short8*)&sG[(wn + j * 16 + lr) * 40 + quad * 8];
            short8 bu = *(const short8*)&sU[(wn + j * 16 + lr) * 40 + quad * 8];
#pragma unroll
            for (int i = 0; i < 4; i++) {
                accg[i][j] = __builtin_amdgcn_mfma_f32_16x16x32_bf16(af[i], bg, accg[i][j], 0, 0, 0);
                accu[i][j] = __builtin_amdgcn_mfma_f32_16x16x32_bf16(af[i], bu, accu[i][j], 0, 0, 0);
            }
        }
    }
#pragma unroll
    for (int i = 0; i < 4; i++) {
#pragma unroll
        for (int r = 0; r < 4; r++) {
            const int pos = m0 + wm + i * 16 + quad * 4 + r;
            const int tok = rowmap[pos];
            const float wc = (tok >= 0) ? comb[tok * NE + e] : 0.f;
#pragma unroll
            for (int j = 0; j < 2; j++) {
                const float g = accg[i][j][r];
                const float u = accu[i][j][r];
                const float h = (g / (1.f + __expf(-g))) * u * wc;
                Hp[(size_t)pos * Ff + (n0 + wn + j * 16 + lr)] = f2bf(h);
            }
        }
    }
}

// ---------------- GEMM2: Op[pos] = Hp[pos] @ Wd_e (native fp32 Wd, packed bf16 out) ----------------
__global__ __launch_bounds__(256, 3) void gemm2_kernel(
    const unsigned short* __restrict__ Hp,
    const float* __restrict__ Wd, const float* __restrict__ sWd,   // native [F][D]
    const int* __restrict__ blocktab,
    const int* __restrict__ meta,
    unsigned short* __restrict__ Op)          // [MAXROWS][D] bf16 packed
{
    if ((int)blockIdx.y >= meta[0]) return;
    __shared__ unsigned short sMem[4096 + 128 * 40];   // sA [128*32] | sB [128][40]
    unsigned short* sA = sMem;
    unsigned short* sB = sMem + 4096;
    const int info = blocktab[blockIdx.y];
    const int e  = info >> 20;
    const int m0 = info & 0xFFFFF;
    const int n0 = blockIdx.x * 128;
    const int tid = threadIdx.x;
    const int lane = tid & 63, wv = tid >> 6;
    const int wm = (wv >> 1) * 64, wn = (wv & 1) * 64;
    const int lr = lane & 15, quad = lane >> 4;

    const unsigned short* Ab = Hp + (size_t)m0 * Ff;
    const float* Dsrc = (e < Ee) ? (Wd + (size_t)e * Ff * Dd) : sWd;
    const int sx = tid & 31, sy = tid >> 5;           // 32 cols-groups x 8 k-groups
    const float* psrc = Dsrc + (size_t)(sy * 4) * Dd + n0 + sx * 4;
    unsigned short* sDst = sB + (sx * 4) * 40 + sy * 4;

    const int l0 = tid * 8;
    const int r0 = l0 >> 5, c0 = l0 & 31;
    const int l1 = l0 + 2048;
    const int r1 = r0 + 64;

    floatx4 pre[4];
#pragma unroll
    for (int i = 0; i < 4; i++) pre[i] = *(const floatx4*)(psrc + (size_t)i * Dd);

    floatx4 acc[4][4];
#pragma unroll
    for (int i = 0; i < 4; i++)
#pragma unroll
        for (int j = 0; j < 4; j++) acc[i][j] = (floatx4){0.f, 0.f, 0.f, 0.f};

    for (int k0 = 0; k0 < Ff; k0 += 32) {
        __syncthreads();
#pragma unroll
        for (int jj = 0; jj < 4; jj++) {
            ushort4 w;
            w.x = f2bf(pre[0][jj]); w.y = f2bf(pre[1][jj]);
            w.z = f2bf(pre[2][jj]); w.w = f2bf(pre[3][jj]);
            *(ushort4*)&sDst[jj * 40] = w;
        }
        gld16(Ab + (size_t)r0 * Ff + k0 + c0, &sA[l0]);
        gld16(Ab + (size_t)r1 * Ff + k0 + c0, &sA[l1]);
        if (k0 + 32 < Ff) {
            const float* np = psrc + (size_t)(k0 + 32) * Dd;
#pragma unroll
            for (int i = 0; i < 4; i++) pre[i] = *(const floatx4*)(np + (size_t)i * Dd);
        }
        __syncthreads();
        short8 af[4];
#pragma unroll
        for (int i = 0; i < 4; i++)
            af[i] = *(const short8*)&sA[(wm + i * 16 + lr) * 32 + quad * 8];
#pragma unroll
        for (int j = 0; j < 4; j++) {
            short8 bf = *(const short8*)&sB[(wn + j * 16 + lr) * 40 + quad * 8];
#pragma unroll
            for (int i = 0; i < 4; i++)
                acc[i][j] = __builtin_amdgcn_mfma_f32_16x16x32_bf16(af[i], bf, acc[i][j], 0, 0, 0);
        }
    }
    // epilogue: per-wave 64x64 bf16 tile staged through LDS, coalesced ushort8 stores
    unsigned short* sOut = sMem + wv * 2048;        // 4 KB per wave (32 rows x 64 cols)
    __syncthreads();                                // K-loop LDS reads done
#pragma unroll
    for (int h = 0; h < 2; h++) {
#pragma unroll
        for (int ii = 0; ii < 2; ii++) {
            const int i = h * 2 + ii;
#pragma unroll
            for (int r = 0; r < 4; r++) {
                const int lrow = ii * 16 + quad * 4 + r;
#pragma unroll
                for (int j = 0; j < 4; j++)
                    sOut[lrow * 64 + j * 16 + lr] = f2bf(acc[i][j][r]);
            }
        }
        __syncthreads();
        const int prow0 = m0 + wm + h * 32;
#pragma unroll
        for (int it = 0; it < 4; it++) {
            const int idx = it * 512 + lane * 8;
            const int row = idx >> 6, col = idx & 63;
            ushort8v vv = *(const ushort8v*)&sOut[row * 64 + col];
            *(ushort8v*)&Op[(size_t)(prow0 + row) * Dd + n0 + wn + col] = vv;
        }
        __syncthreads();
    }
}

// ---------------- reduce: out[t] = sum of the token's 5 packed Op rows ----------------
__global__ __launch_bounds__(256) void reduce_kernel(
    const unsigned short* __restrict__ Op, const int* __restrict__ tokpos,
    float* __restrict__ out)
{
    const int t = blockIdx.x;
    const int c = threadIdx.x * 8;
    int ps[5];
#pragma unroll
    for (int k = 0; k < 5; k++) ps[k] = tokpos[t * 8 + k];
    float s[8];
#pragma unroll
    for (int j = 0; j < 8; j++) s[j] = 0.f;
#pragma unroll
    for (int k = 0; k < 5; k++) {
        ushort8v v = *(const ushort8v*)&Op[(size_t)ps[k] * Dd + c];
#pragma unroll
        for (int j = 0; j < 8; j++) s[j] += bf2f(v[j]);
    }
    *(floatx4*)(out + (size_t)t * Dd + c) = *(floatx4*)&s[0];
    *(floatx4*)(out + (size_t)t * Dd + c + 4) = *(floatx4*)&s[4];
}

extern "C" void kernel_launch(void* const* d_in, const int* in_sizes, int n_in,
                              void* d_out, int out_size, void* d_ws, size_t ws_size,
                              hipStream_t stream) {
    const float* x   = (const float*)d_in[0];
    const float* gw  = (const float*)d_in[1];
    const float* Wg  = (const float*)d_in[2];
    const float* Wu  = (const float*)d_in[3];
    const float* Wd  = (const float*)d_in[4];
    const float* sWg = (const float*)d_in[5];
    const float* sWu = (const float*)d_in[6];
    const float* sWd = (const float*)d_in[7];
    const float* sgw = (const float*)d_in[8];
    float* out = (float*)d_out;

    // workspace layout (bytes)
    char* ws = (char*)d_ws;
    unsigned short* xb  = (unsigned short*)(ws);                 //  8,388,608  x bf16 hi [T][D]
    unsigned short* xl  = (unsigned short*)(ws + 8388608);       //  8,388,608  x bf16 lo [T][D]
    unsigned short* Op  = (unsigned short*)(ws + 16777216);      // 50,331,648  [MAXROWS][D]
    unsigned short* Hp  = (unsigned short*)(ws + 67108864);      // 12,582,912  packed [MAXROWS][F]
    float* part   = (float*)(ws + 79691776);                     //  2,097,152  [8][T][32]
    unsigned short* gB  = (unsigned short*)(ws + 81788928);      //    262,144  [2][32][D]
    float* comb   = (float*)(ws + 82051072);                     //    139,264  [T][NE]
    int* selids   = (int*)(ws + 82190336);                       //     32,768  [T][4]
    int* counts   = (int*)(ws + 82223104);                       //         64
    int* off      = (int*)(ws + 82223168);                       //        128
    int* cursor   = (int*)(ws + 82223296);                       //         64
    int* meta     = (int*)(ws + 82223360);                       //         64
    int* blocktab = (int*)(ws + 82223424);                       //        512
    int* rowmap   = (int*)(ws + 82223936);                       //     49,152 [MAXROWS]
    int* tokpos   = (int*)(ws + 82273088);                       //     65,536 [T][8]

    splitcast_x<<<Tt * Dd / 2048, 256, 0, stream>>>(x, xb, xl);
    splitg_kernel<<<32, 256, 0, stream>>>(gw, sgw, gB);
    logits_kernel<<<dim3(Tt / 128, 8), 256, 0, stream>>>(xb, xl, gB, part);
    hipMemsetAsync(counts, 0, 64, stream);
    topk_kernel<<<Tt / 64, 64, 0, stream>>>(part, comb, selids, counts);
    offsets_kernel<<<1, 1, 0, stream>>>(counts, off, cursor, blocktab, meta);
    hipMemsetAsync(rowmap, 0xFF, MAXROWS * sizeof(int), stream);
    scatter_kernel<<<8, 256, 0, stream>>>(selids, off, cursor, rowmap, tokpos);
    gemm1_kernel<<<dim3(Ff / 64, MAXTILES), 256, 0, stream>>>(
        xb, Wg, sWg, Wu, sWu, comb, rowmap, blocktab, meta, Hp);
    gemm2_kernel<<<dim3(Dd / 128, MAXTILES), 256, 0, stream>>>(
        Hp, Wd, sWd, blocktab, meta, Op);
    reduce_kernel<<<Tt, 256, 0, stream>>>(Op, tokpos, out);
}

// Round 7
// 409.340 us; speedup vs baseline: 1.6383x; 1.0078x over previous
//
#include <hip/hip_runtime.h>
#include <hip/hip_bf16.h>

#define Tt 2048
#define Dd 2048
#define Ff 512
#define Ee 16
#define NE 17                    // 16 routed experts + 1 shared
#define MAXROWS 12288            // 80 routed tiles*128 + 16 shared tiles*128
#define MAXTILES 96

typedef __attribute__((ext_vector_type(8))) short short8;
typedef __attribute__((ext_vector_type(8))) unsigned short ushort8v;
typedef __attribute__((ext_vector_type(4))) float floatx4;

#define AS1 __attribute__((address_space(1)))
#define AS3 __attribute__((address_space(3)))

__device__ __forceinline__ unsigned short f2bf(float f) {
    union { float f; unsigned u; } v; v.f = f;
    unsigned r = v.u + 0x7FFFu + ((v.u >> 16) & 1u);   // RNE
    return (unsigned short)(r >> 16);
}
__device__ __forceinline__ float bf2f(unsigned short h) {
    union { unsigned u; float f; } v; v.u = ((unsigned)h) << 16;
    return v.f;
}

__device__ __forceinline__ void gld16(const unsigned short* g, unsigned short* l) {
    __builtin_amdgcn_global_load_lds((const AS1 void*)g, (AS3 void*)l, 16, 0, 0);
}

// ---------------- split-cast x -> bf16 hi + bf16 lo ----------------
__global__ void splitcast_x(const float* __restrict__ x, unsigned short* __restrict__ xh,
                            unsigned short* __restrict__ xl) {
    int i = (blockIdx.x * 256 + threadIdx.x) * 8;
    float v[8];
    *(floatx4*)&v[0] = *(const floatx4*)(x + i);
    *(floatx4*)&v[4] = *(const floatx4*)(x + i + 4);
    ushort8v h, l;
#pragma unroll
    for (int j = 0; j < 8; j++) {
        unsigned short hb = f2bf(v[j]);
        h[j] = hb;
        l[j] = f2bf(v[j] - bf2f(hb));
    }
    *(ushort8v*)(xh + i) = h;
    *(ushort8v*)(xl + i) = l;
}

// ---------------- split gate weights into gB[2][32][2048] (hi,lo), rows 17..31 zero ----------------
__global__ void splitg_kernel(const float* __restrict__ gw, const float* __restrict__ sgw,
                              unsigned short* __restrict__ gB) {
    int z = blockIdx.x;                // 0..31
    int i = threadIdx.x * 8;
    ushort8v h = {0,0,0,0,0,0,0,0}, l = {0,0,0,0,0,0,0,0};
    if (z < NE) {
        const float* src = (z < Ee) ? (gw + (size_t)z * Dd) : sgw;
        float v[8];
        *(floatx4*)&v[0] = *(const floatx4*)(src + i);
        *(floatx4*)&v[4] = *(const floatx4*)(src + i + 4);
#pragma unroll
        for (int j = 0; j < 8; j++) {
            unsigned short hb = f2bf(v[j]);
            h[j] = hb;
            l[j] = f2bf(v[j] - bf2f(hb));
        }
    }
    *(ushort8v*)(gB + (size_t)z * Dd + i) = h;
    *(ushort8v*)(gB + 32 * Dd + (size_t)z * Dd + i) = l;
}

// ---------------- logits GEMM: part[kb][t][n] = sum_k x*gw (hi/lo compensated) ----------------
__global__ __launch_bounds__(256) void logits_kernel(
    const unsigned short* __restrict__ xh, const unsigned short* __restrict__ xl,
    const unsigned short* __restrict__ gB, float* __restrict__ part) {
    __shared__ unsigned short sAh[128 * 32];
    __shared__ unsigned short sAl[128 * 32];
    __shared__ unsigned short sB[2048];     // [0..1023] hi 32x32, [1024..2047] lo 32x32
    const int m0 = blockIdx.x * 128;
    const int kb = blockIdx.y;
    const int k00 = kb * 256;
    const int tid = threadIdx.x;
    const int lane = tid & 63, wv = tid >> 6;
    const int lr = lane & 15, quad = lane >> 4;

    const int l0 = tid * 8;
    const int r0 = l0 >> 5, c0 = l0 & 31;
    const int l1 = l0 + 2048;
    const int r1 = r0 + 64;
    const int br = (tid >> 2) & 31, bc = (tid & 3) * 8;
    const unsigned short* bsrc = gB + ((tid >= 128) ? 32 * Dd : 0) + (size_t)br * Dd + bc;

    floatx4 acc[2][2];
#pragma unroll
    for (int i = 0; i < 2; i++)
#pragma unroll
        for (int j = 0; j < 2; j++) acc[i][j] = (floatx4){0.f, 0.f, 0.f, 0.f};

    for (int kk = 0; kk < 256; kk += 32) {
        __syncthreads();
        gld16(xh + (size_t)(m0 + r0) * Dd + k00 + kk + c0, &sAh[l0]);
        gld16(xh + (size_t)(m0 + r1) * Dd + k00 + kk + c0, &sAh[l1]);
        gld16(xl + (size_t)(m0 + r0) * Dd + k00 + kk + c0, &sAl[l0]);
        gld16(xl + (size_t)(m0 + r1) * Dd + k00 + kk + c0, &sAl[l1]);
        gld16(bsrc + k00 + kk, &sB[l0 & 2047]);
        __syncthreads();
#pragma unroll
        for (int mi = 0; mi < 2; mi++) {
            const int ar = wv * 32 + mi * 16 + lr;
            short8 ah = *(const short8*)&sAh[ar * 32 + quad * 8];
            short8 al = *(const short8*)&sAl[ar * 32 + quad * 8];
#pragma unroll
            for (int nj = 0; nj < 2; nj++) {
                short8 bh = *(const short8*)&sB[(nj * 16 + lr) * 32 + quad * 8];
                short8 bl = *(const short8*)&sB[1024 + (nj * 16 + lr) * 32 + quad * 8];
                acc[mi][nj] = __builtin_amdgcn_mfma_f32_16x16x32_bf16(ah, bh, acc[mi][nj], 0, 0, 0);
                acc[mi][nj] = __builtin_amdgcn_mfma_f32_16x16x32_bf16(ah, bl, acc[mi][nj], 0, 0, 0);
                acc[mi][nj] = __builtin_amdgcn_mfma_f32_16x16x32_bf16(al, bh, acc[mi][nj], 0, 0, 0);
            }
        }
    }
#pragma unroll
    for (int mi = 0; mi < 2; mi++)
#pragma unroll
        for (int r = 0; r < 4; r++) {
            const int t = m0 + wv * 32 + mi * 16 + quad * 4 + r;
#pragma unroll
            for (int nj = 0; nj < 2; nj++)
                part[((size_t)kb * Tt + t) * 32 + nj * 16 + lr] = acc[mi][nj][r];
        }
}

// ---------------- topk: reduce split-K partials, softmax, top4, shared gate ----------------
__global__ void topk_kernel(const float* __restrict__ part, float* __restrict__ comb,
                            int* __restrict__ selids, int* __restrict__ counts) {
    const int t = blockIdx.x * 64 + threadIdx.x;
    float lg[20];
#pragma unroll
    for (int j = 0; j < 20; j++) lg[j] = 0.f;
#pragma unroll
    for (int kb = 0; kb < 8; kb++) {
        const float* p = part + ((size_t)kb * Tt + t) * 32;
#pragma unroll
        for (int q = 0; q < 5; q++) {
            floatx4 a = *(const floatx4*)(p + q * 4);
            lg[q * 4 + 0] += a.x; lg[q * 4 + 1] += a.y;
            lg[q * 4 + 2] += a.z; lg[q * 4 + 3] += a.w;
        }
    }
    float mx = lg[0];
    for (int e = 1; e < Ee; e++) mx = fmaxf(mx, lg[e]);
    float p[Ee]; float sum = 0.f;
    for (int e = 0; e < Ee; e++) { p[e] = __expf(lg[e] - mx); sum += p[e]; }
    float inv = 1.f / sum;
    for (int e = 0; e < Ee; e++) p[e] *= inv;
    bool sel[Ee];
    for (int e = 0; e < Ee; e++) sel[e] = false;
    int ids[4];
    float ssum = 0.f;
    for (int k = 0; k < 4; k++) {
        int bi = 0; float bv = -1.f;
        for (int e = 0; e < Ee; e++)
            if (!sel[e] && p[e] > bv) { bv = p[e]; bi = e; }
        sel[bi] = true; ids[k] = bi; ssum += bv;
    }
    float rinv = 1.f / ssum;
    for (int e = 0; e < Ee; e++) comb[t * NE + e] = sel[e] ? p[e] * rinv : 0.f;
    comb[t * NE + Ee] = 1.f / (1.f + __expf(-lg[16]));
#pragma unroll
    for (int k = 0; k < 4; k++) {
        selids[t * 4 + k] = ids[k];
        atomicAdd(&counts[ids[k]], 1);
    }
}

// ---------------- offsets: tile-padded exclusive scan + block table ----------------
__global__ void offsets_kernel(const int* __restrict__ counts, int* __restrict__ off,
                               int* __restrict__ cursor, int* __restrict__ blocktab,
                               int* __restrict__ meta) {
    int acc = 0, nt = 0;
    for (int e = 0; e < NE; e++) {
        int c = (e < Ee) ? counts[e] : Tt;
        off[e] = acc;
        if (e < Ee) cursor[e] = 0;
        int tiles = (c + 127) >> 7;
        for (int tl = 0; tl < tiles; tl++) blocktab[nt++] = (e << 20) | (acc + tl * 128);
        acc += tiles << 7;
    }
    meta[0] = nt;
}

// ---------------- scatter: rowmap (pos -> token) + tokpos (token -> its 5 positions) ----------------
__global__ void scatter_kernel(const int* __restrict__ selids, const int* __restrict__ off,
                               int* __restrict__ cursor, int* __restrict__ rowmap,
                               int* __restrict__ tokpos) {
    int t = blockIdx.x * 256 + threadIdx.x;
    if (t >= Tt) return;
#pragma unroll
    for (int k = 0; k < 4; k++) {
        int e = selids[t * 4 + k];
        int r = atomicAdd(&cursor[e], 1);
        int pos = off[e] + r;
        rowmap[pos] = t;
        tokpos[t * 8 + k] = pos;
    }
    int sp = off[Ee] + t;
    rowmap[sp] = t;            // shared expert: identity
    tokpos[t * 8 + 4] = sp;
}

// ---------------- GEMM1: Hp[pos][f] = comb * silu(x@Wg_e) * (x@Wu_e) ----------------
// 128x64 tile. Native [D][F] fp32 weights staged via registers, bf16-converted,
// 4x4 micro-transposed into [n][k] LDS (stride 40). k-group placement XOR-swizzled
// with even key ((n>>2)&3)*2: writes spread to 4 lanes/bank (was 8-way), reads stay
// 16B-contiguous/aligned and unswizzle with a row-independent koff.
__global__ __launch_bounds__(256, 3) void gemm1_kernel(
    const unsigned short* __restrict__ xb,
    const float* __restrict__ Wg, const float* __restrict__ sWg,
    const float* __restrict__ Wu, const float* __restrict__ sWu,
    const float* __restrict__ comb,
    const int* __restrict__ rowmap,
    const int* __restrict__ blocktab,
    const int* __restrict__ meta,
    unsigned short* __restrict__ Hp)
{
    if ((int)blockIdx.y >= meta[0]) return;
    __shared__ unsigned short sA[128 * 32];   // A tile (gld16 lane-contiguous layout)
    __shared__ unsigned short sG[64 * 40];    // B^T tile [n][k], stride 40, swizzled k-groups
    __shared__ unsigned short sU[64 * 40];
    const int info = blocktab[blockIdx.y];
    const int e  = info >> 20;
    const int m0 = info & 0xFFFFF;
    const int n0 = blockIdx.x * 64;
    const int tid = threadIdx.x;
    const int lane = tid & 63, wv = tid >> 6;
    const int wm = (wv >> 1) * 64, wn = (wv & 1) * 32;
    const int lr = lane & 15, quad = lane >> 4;

    const float* Gsrc = (e < Ee) ? (Wg + (size_t)e * Dd * Ff) : sWg;
    const float* Usrc = (e < Ee) ? (Wu + (size_t)e * Dd * Ff) : sWu;
    // staging: threads 0..127 stage G, 128..255 stage U; each owns a 4k x 4n block
    const int sx = tid & 15, sy = (tid >> 4) & 7, plane = tid >> 7;
    const float* psrc = (plane ? Usrc : Gsrc) + (size_t)(sy * 4) * Ff + n0 + sx * 4;
    unsigned short* sDst = (plane ? sU : sG) + (sx * 4) * 40 + ((sy ^ ((sx & 3) * 2)) * 4);
    // read-side unswizzle offset (key = ((row>>2)&3)*2 = (lr>>2)*2 for all fragments)
    const int koff = ((quad * 2) ^ ((lr >> 2) * 2)) * 4;

    const int l0 = tid * 8;
    const int r0 = l0 >> 5, c0 = l0 & 31;
    const int l1 = l0 + 2048;
    const int r1 = r0 + 64;
    const int tk0 = rowmap[m0 + r0];
    const int tk1 = rowmap[m0 + r1];
    const unsigned short* a0 = xb + (size_t)(tk0 < 0 ? 0 : tk0) * Dd + c0;
    const unsigned short* a1 = xb + (size_t)(tk1 < 0 ? 0 : tk1) * Dd + c0;

    floatx4 pre[4];
#pragma unroll
    for (int i = 0; i < 4; i++) pre[i] = *(const floatx4*)(psrc + (size_t)i * Ff);

    floatx4 accg[4][2], accu[4][2];
#pragma unroll
    for (int i = 0; i < 4; i++)
#pragma unroll
        for (int j = 0; j < 2; j++) {
            accg[i][j] = (floatx4){0.f, 0.f, 0.f, 0.f};
            accu[i][j] = (floatx4){0.f, 0.f, 0.f, 0.f};
        }

    for (int k0 = 0; k0 < Dd; k0 += 32) {
        __syncthreads();
        // convert + micro-transpose write: ushort4 along k at row (sx*4+jj)
#pragma unroll
        for (int jj = 0; jj < 4; jj++) {
            ushort4 w;
            w.x = f2bf(pre[0][jj]); w.y = f2bf(pre[1][jj]);
            w.z = f2bf(pre[2][jj]); w.w = f2bf(pre[3][jj]);
            *(ushort4*)&sDst[jj * 40] = w;
        }
        gld16(a0 + k0, &sA[l0]);
        gld16(a1 + k0, &sA[l1]);
        if (k0 + 32 < Dd) {
            const float* np = psrc + (size_t)(k0 + 32) * Ff;
#pragma unroll
            for (int i = 0; i < 4; i++) pre[i] = *(const floatx4*)(np + (size_t)i * Ff);
        }
        __syncthreads();
        short8 af[4];
#pragma unroll
        for (int i = 0; i < 4; i++)
            af[i] = *(const short8*)&sA[(wm + i * 16 + lr) * 32 + quad * 8];
#pragma unroll
        for (int j = 0; j < 2; j++) {
            short8 bg = *(const short8*)&sG[(wn + j * 16 + lr) * 40 + koff];
            short8 bu = *(const short8*)&sU[(wn + j * 16 + lr) * 40 + koff];
#pragma unroll
            for (int i = 0; i < 4; i++) {
                accg[i][j] = __builtin_amdgcn_mfma_f32_16x16x32_bf16(af[i], bg, accg[i][j], 0, 0, 0);
                accu[i][j] = __builtin_amdgcn_mfma_f32_16x16x32_bf16(af[i], bu, accu[i][j], 0, 0, 0);
            }
        }
    }
#pragma unroll
    for (int i = 0; i < 4; i++) {
#pragma unroll
        for (int r = 0; r < 4; r++) {
            const int pos = m0 + wm + i * 16 + quad * 4 + r;
            const int tok = rowmap[pos];
            const float wc = (tok >= 0) ? comb[tok * NE + e] : 0.f;
#pragma unroll
            for (int j = 0; j < 2; j++) {
                const float g = accg[i][j][r];
                const float u = accu[i][j][r];
                const float h = (g / (1.f + __expf(-g))) * u * wc;
                Hp[(size_t)pos * Ff + (n0 + wn + j * 16 + lr)] = f2bf(h);
            }
        }
    }
}

// ---------------- GEMM2: Op[pos] = Hp[pos] @ Wd_e (native fp32 Wd, packed bf16 out) ----------------
__global__ __launch_bounds__(256, 3) void gemm2_kernel(
    const unsigned short* __restrict__ Hp,
    const float* __restrict__ Wd, const float* __restrict__ sWd,   // native [F][D]
    const int* __restrict__ blocktab,
    const int* __restrict__ meta,
    unsigned short* __restrict__ Op)          // [MAXROWS][D] bf16 packed
{
    if ((int)blockIdx.y >= meta[0]) return;
    __shared__ unsigned short sMem[4096 + 128 * 40];   // sA [128*32] | sB [128][40]
    unsigned short* sA = sMem;
    unsigned short* sB = sMem + 4096;
    const int info = blocktab[blockIdx.y];
    const int e  = info >> 20;
    const int m0 = info & 0xFFFFF;
    const int n0 = blockIdx.x * 128;
    const int tid = threadIdx.x;
    const int lane = tid & 63, wv = tid >> 6;
    const int wm = (wv >> 1) * 64, wn = (wv & 1) * 64;
    const int lr = lane & 15, quad = lane >> 4;

    const unsigned short* Ab = Hp + (size_t)m0 * Ff;
    const float* Dsrc = (e < Ee) ? (Wd + (size_t)e * Ff * Dd) : sWd;
    // plane-split staging: threads 0..127 stage n-half 0, 128..255 stage n-half 1;
    // each owns a 4k x 4n block -> sy spans 0..7 within a wave (swizzle -> 4-way)
    const int sx = tid & 15, sy = (tid >> 4) & 7, plane = tid >> 7;
    const float* psrc = Dsrc + (size_t)(sy * 4) * Dd + n0 + plane * 64 + sx * 4;
    unsigned short* sDst = sB + (plane * 64 + sx * 4) * 40 + ((sy ^ ((sx & 3) * 2)) * 4);
    const int koff = ((quad * 2) ^ ((lr >> 2) * 2)) * 4;

    const int l0 = tid * 8;
    const int r0 = l0 >> 5, c0 = l0 & 31;
    const int l1 = l0 + 2048;
    const int r1 = r0 + 64;

    floatx4 pre[4];
#pragma unroll
    for (int i = 0; i < 4; i++) pre[i] = *(const floatx4*)(psrc + (size_t)i * Dd);

    floatx4 acc[4][4];
#pragma unroll
    for (int i = 0; i < 4; i++)
#pragma unroll
        for (int j = 0; j < 4; j++) acc[i][j] = (floatx4){0.f, 0.f, 0.f, 0.f};

    for (int k0 = 0; k0 < Ff; k0 += 32) {
        __syncthreads();
#pragma unroll
        for (int jj = 0; jj < 4; jj++) {
            ushort4 w;
            w.x = f2bf(pre[0][jj]); w.y = f2bf(pre[1][jj]);
            w.z = f2bf(pre[2][jj]); w.w = f2bf(pre[3][jj]);
            *(ushort4*)&sDst[jj * 40] = w;
        }
        gld16(Ab + (size_t)r0 * Ff + k0 + c0, &sA[l0]);
        gld16(Ab + (size_t)r1 * Ff + k0 + c0, &sA[l1]);
        if (k0 + 32 < Ff) {
            const float* np = psrc + (size_t)(k0 + 32) * Dd;
#pragma unroll
            for (int i = 0; i < 4; i++) pre[i] = *(const floatx4*)(np + (size_t)i * Dd);
        }
        __syncthreads();
        short8 af[4];
#pragma unroll
        for (int i = 0; i < 4; i++)
            af[i] = *(const short8*)&sA[(wm + i * 16 + lr) * 32 + quad * 8];
#pragma unroll
        for (int j = 0; j < 4; j++) {
            short8 bf = *(const short8*)&sB[(wn + j * 16 + lr) * 40 + koff];
#pragma unroll
            for (int i = 0; i < 4; i++)
                acc[i][j] = __builtin_amdgcn_mfma_f32_16x16x32_bf16(af[i], bf, acc[i][j], 0, 0, 0);
        }
    }
    // epilogue: per-wave 64x64 bf16 tile staged through LDS, coalesced ushort8 stores
    unsigned short* sOut = sMem + wv * 2048;        // 4 KB per wave (32 rows x 64 cols)
    __syncthreads();                                // K-loop LDS reads done
#pragma unroll
    for (int h = 0; h < 2; h++) {
#pragma unroll
        for (int ii = 0; ii < 2; ii++) {
            const int i = h * 2 + ii;
#pragma unroll
            for (int r = 0; r < 4; r++) {
                const int lrow = ii * 16 + quad * 4 + r;
#pragma unroll
                for (int j = 0; j < 4; j++)
                    sOut[lrow * 64 + j * 16 + lr] = f2bf(acc[i][j][r]);
            }
        }
        __syncthreads();
        const int prow0 = m0 + wm + h * 32;
#pragma unroll
        for (int it = 0; it < 4; it++) {
            const int idx = it * 512 + lane * 8;
            const int row = idx >> 6, col = idx & 63;
            ushort8v vv = *(const ushort8v*)&sOut[row * 64 + col];
            *(ushort8v*)&Op[(size_t)(prow0 + row) * Dd + n0 + wn + col] = vv;
        }
        __syncthreads();
    }
}

// ---------------- reduce: out[t] = sum of the token's 5 packed Op rows ----------------
__global__ __launch_bounds__(256) void reduce_kernel(
    const unsigned short* __restrict__ Op, const int* __restrict__ tokpos,
    float* __restrict__ out)
{
    const int t = blockIdx.x;
    const int c = threadIdx.x * 8;
    int ps[5];
#pragma unroll
    for (int k = 0; k < 5; k++) ps[k] = tokpos[t * 8 + k];
    float s[8];
#pragma unroll
    for (int j = 0; j < 8; j++) s[j] = 0.f;
#pragma unroll
    for (int k = 0; k < 5; k++) {
        ushort8v v = *(const ushort8v*)&Op[(size_t)ps[k] * Dd + c];
#pragma unroll
        for (int j = 0; j < 8; j++) s[j] += bf2f(v[j]);
    }
    *(floatx4*)(out + (size_t)t * Dd + c) = *(floatx4*)&s[0];
    *(floatx4*)(out + (size_t)t * Dd + c + 4) = *(floatx4*)&s[4];
}

extern "C" void kernel_launch(void* const* d_in, const int* in_sizes, int n_in,
                              void* d_out, int out_size, void* d_ws, size_t ws_size,
                              hipStream_t stream) {
    const float* x   = (const float*)d_in[0];
    const float* gw  = (const float*)d_in[1];
    const float* Wg  = (const float*)d_in[2];
    const float* Wu  = (const float*)d_in[3];
    const float* Wd  = (const float*)d_in[4];
    const float* sWg = (const float*)d_in[5];
    const float* sWu = (const float*)d_in[6];
    const float* sWd = (const float*)d_in[7];
    const float* sgw = (const float*)d_in[8];
    float* out = (float*)d_out;

    // workspace layout (bytes)
    char* ws = (char*)d_ws;
    unsigned short* xb  = (unsigned short*)(ws);                 //  8,388,608  x bf16 hi [T][D]
    unsigned short* xl  = (unsigned short*)(ws + 8388608);       //  8,388,608  x bf16 lo [T][D]
    unsigned short* Op  = (unsigned short*)(ws + 16777216);      // 50,331,648  [MAXROWS][D]
    unsigned short* Hp  = (unsigned short*)(ws + 67108864);      // 12,582,912  packed [MAXROWS][F]
    float* part   = (float*)(ws + 79691776);                     //  2,097,152  [8][T][32]
    unsigned short* gB  = (unsigned short*)(ws + 81788928);      //    262,144  [2][32][D]
    float* comb   = (float*)(ws + 82051072);                     //    139,264  [T][NE]
    int* selids   = (int*)(ws + 82190336);                       //     32,768  [T][4]
    int* counts   = (int*)(ws + 82223104);                       //         64
    int* off      = (int*)(ws + 82223168);                       //        128
    int* cursor   = (int*)(ws + 82223296);                       //         64
    int* meta     = (int*)(ws + 82223360);                       //         64
    int* blocktab = (int*)(ws + 82223424);                       //        512
    int* rowmap   = (int*)(ws + 82223936);                       //     49,152 [MAXROWS]
    int* tokpos   = (int*)(ws + 82273088);                       //     65,536 [T][8]

    splitcast_x<<<Tt * Dd / 2048, 256, 0, stream>>>(x, xb, xl);
    splitg_kernel<<<32, 256, 0, stream>>>(gw, sgw, gB);
    logits_kernel<<<dim3(Tt / 128, 8), 256, 0, stream>>>(xb, xl, gB, part);
    hipMemsetAsync(counts, 0, 64, stream);
    topk_kernel<<<Tt / 64, 64, 0, stream>>>(part, comb, selids, counts);
    offsets_kernel<<<1, 1, 0, stream>>>(counts, off, cursor, blocktab, meta);
    hipMemsetAsync(rowmap, 0xFF, MAXROWS * sizeof(int), stream);
    scatter_kernel<<<8, 256, 0, stream>>>(selids, off, cursor, rowmap, tokpos);
    gemm1_kernel<<<dim3(Ff / 64, MAXTILES), 256, 0, stream>>>(
        xb, Wg, sWg, Wu, sWu, comb, rowmap, blocktab, meta, Hp);
    gemm2_kernel<<<dim3(Dd / 128, MAXTILES), 256, 0, stream>>>(
        Hp, Wd, sWd, blocktab, meta, Op);
    reduce_kernel<<<Tt, 256, 0, stream>>>(Op, tokpos, out);
}